// Round 9
// baseline (297.326 us; speedup 1.0000x reference)
//
#include <hip/hip_runtime.h>
#include <hip/hip_bf16.h>
#include <cstdint>
#include <cstddef>

// ---------------------------------------------------------------------------
// MultiheadSelfAttention fused pipeline for MI355X (gfx950)
// Head (b,h) = contiguous slab of the FLAT projection output (torch-faithful
// reshape without transpose): slab = (2048,64) row-major at bh*131072.
// Q pre-scaled by 0.125*log2(e) in gemm_qkv; max-free exp2 softmax.
// V transposed per head by transpose_v (slab view -> [d][s]).
// Round 9: BARRIER-FREE attention — K/V fragments loaded directly from
// global (L1/L2-resident; every wave needs the whole tile anyway, so LDS
// staging only doubled traffic and forced lockstep barriers). Only the
// per-wave P round-trip stays in LDS. 1-wave blocks + head-sharing swizzle
// so co-resident blocks on a CU reuse the same K/V tiles in L1.
// ---------------------------------------------------------------------------

#define SEQ   2048
#define DIM   1024
#define NHEAD 16
#define HDIM  64
#define ROWS  4096   // B*S

#define QSCALE 0.1803368801111204f   // 0.125 * log2(e)

typedef __attribute__((ext_vector_type(8))) __bf16 bf16x8;
typedef __attribute__((ext_vector_type(4))) float floatx4;
typedef __attribute__((ext_vector_type(8))) unsigned short ushortx8;

__device__ __forceinline__ unsigned short f2bf(float f) {
  unsigned int u = __float_as_uint(f);
  u += 0x7FFFu + ((u >> 16) & 1u);   // round-to-nearest-even
  return (unsigned short)(u >> 16);
}

__device__ __forceinline__ unsigned int pk2bf(float a, float b) {
  float2 f; f.x = a; f.y = b;                       // x -> low 16
  __hip_bfloat162 h = __float22bfloat162_rn(f);
  return *(unsigned int*)&h;
}

// ---- fp32 -> bf16 elementwise convert (vectorized float4 -> 4x bf16) -------
__global__ __launch_bounds__(256) void cvt_bf16(const float* __restrict__ in,
                                                unsigned short* __restrict__ out,
                                                int n4) {
  int i = blockIdx.x * 256 + threadIdx.x;
  if (i >= n4) return;
  float4 v = ((const float4*)in)[i];
  ushort4 o;
  o.x = f2bf(v.x); o.y = f2bf(v.y); o.z = f2bf(v.z); o.w = f2bf(v.w);
  ((ushort4*)out)[i] = o;
}

// ---- 4x (1024x1024 fp32 -> transposed bf16), one launch (z = matrix) -------
__global__ __launch_bounds__(256) void transpose_w4(
    const float* __restrict__ Wq, const float* __restrict__ Wk,
    const float* __restrict__ Wv, const float* __restrict__ Wo,
    unsigned short* __restrict__ Wqkvt, unsigned short* __restrict__ Wot) {
  __shared__ float t[32][33];
  const int z = blockIdx.z;
  const float* in = (z == 0) ? Wq : (z == 1) ? Wk : (z == 2) ? Wv : Wo;
  unsigned short* out = (z < 3) ? Wqkvt + (size_t)z * DIM * DIM : Wot;
  const int bx = blockIdx.x * 32, by = blockIdx.y * 32;
  const int tx = threadIdx.x, ty = threadIdx.y;
#pragma unroll
  for (int i = ty; i < 32; i += 8)
    t[i][tx] = in[(size_t)(by + i) * DIM + bx + tx];
  __syncthreads();
#pragma unroll
  for (int i = ty; i < 32; i += 8)
    out[(size_t)(bx + i) * DIM + by + tx] = f2bf(t[tx][i]);
}

// ---- per-head V transpose: slab (2048,64) -> (64,2048), bh = 0..31 ---------
__global__ __launch_bounds__(256) void transpose_v(
    const unsigned short* __restrict__ Vb,   // flat: 32 slabs of 2048x64
    unsigned short* __restrict__ VbT) {      // 32 slabs of 64x2048
  __shared__ unsigned short t[64][65];
  const int bh = blockIdx.y;
  const int s0 = blockIdx.x * 64;
  const int tx = threadIdx.x;                // 0..63
  const int ty = threadIdx.y;                // 0..3
  const unsigned short* src = Vb + (size_t)bh * (SEQ * HDIM);
  unsigned short* dst = VbT + (size_t)bh * (SEQ * HDIM);
#pragma unroll
  for (int i = ty; i < 64; i += 4)
    t[i][tx] = src[(size_t)(s0 + i) * HDIM + tx];
  __syncthreads();
#pragma unroll
  for (int i = ty; i < 64; i += 4)
    dst[(size_t)i * SEQ + s0 + tx] = t[tx][i];
}

// ---------------------------------------------------------------------------
// Fused QKV GEMM. Q written PRE-SCALED by QSCALE (max-free exp2 softmax).
// ---------------------------------------------------------------------------
__global__ __launch_bounds__(256, 3) void gemm_qkv(
    const unsigned short* __restrict__ A,    // 4096 x 1024 bf16
    const unsigned short* __restrict__ Wt,   // 3072 x 1024 bf16
    const float* __restrict__ bq, const float* __restrict__ bk,
    const float* __restrict__ bv,
    unsigned short* __restrict__ Qb, unsigned short* __restrict__ Kb,
    unsigned short* __restrict__ Vb) {
  constexpr int K = DIM;
  __shared__ unsigned short As[128 * 72];
  __shared__ unsigned short Bs[128 * 72];
  const int tid  = threadIdx.x;
  const int lane = tid & 63, wave = tid >> 6;
  const int l16  = lane & 15, quad = lane >> 4;
  const int wm   = (wave & 1) * 64, wn = (wave >> 1) * 64;
  const int tm   = blockIdx.y * 128, tn = blockIdx.x * 128;
  const int srow = tid >> 3, scol = (tid & 7) * 8;

  floatx4 acc[4][4] = {};

  for (int k0 = 0; k0 < K; k0 += 64) {
    __syncthreads();
#pragma unroll
    for (int p = 0; p < 4; ++p) {
      const int row = srow + p * 32;
      *(ushortx8*)&As[row * 72 + scol] =
          *(const ushortx8*)&A[(size_t)(tm + row) * K + k0 + scol];
      *(ushortx8*)&Bs[row * 72 + scol] =
          *(const ushortx8*)&Wt[(size_t)(tn + row) * K + k0 + scol];
    }
    __syncthreads();
#pragma unroll
    for (int step = 0; step < 2; ++step) {
      const int kk = step * 32 + quad * 8;
      bf16x8 af[4], bfr[4];
#pragma unroll
      for (int i = 0; i < 4; ++i)
        af[i] = *(const bf16x8*)&As[(wm + i * 16 + l16) * 72 + kk];
#pragma unroll
      for (int j = 0; j < 4; ++j)
        bfr[j] = *(const bf16x8*)&Bs[(wn + j * 16 + l16) * 72 + kk];
#pragma unroll
      for (int i = 0; i < 4; ++i)
#pragma unroll
        for (int j = 0; j < 4; ++j)
          acc[i][j] = __builtin_amdgcn_mfma_f32_16x16x32_bf16(af[i], bfr[j],
                                                              acc[i][j], 0, 0, 0);
    }
  }

#pragma unroll
  for (int j = 0; j < 4; ++j) {
    const int ng  = tn + wn + j * 16 + l16;   // output channel 0..3071
    const int seg = ng >> 10;                 // 0=Q 1=K 2=V
    const int col = ng & 1023;
    const float* bp    = (seg == 0) ? bq : (seg == 1) ? bk : bv;
    unsigned short* op = (seg == 0) ? Qb : (seg == 1) ? Kb : Vb;
    const float bias = bp[col];
    const float scl  = (seg == 0) ? QSCALE : 1.0f;
#pragma unroll
    for (int i = 0; i < 4; ++i) {
      const int m0 = tm + wm + i * 16 + quad * 4;
#pragma unroll
      for (int r = 0; r < 4; ++r)
        op[(size_t)(m0 + r) * DIM + col] = f2bf((acc[i][j][r] + bias) * scl);
    }
  }
}

// ---- Output projection GEMM: Y = ctx @ Wo + bo. 128x64 tiles -> 512 blocks
// (2/CU; the old 128x128 grid was 256 blocks = 1/CU, occupancy-starved). ----
__global__ __launch_bounds__(256) void gemm_o(
    const unsigned short* __restrict__ A,    // 4096 x 1024 bf16 (ctx)
    const unsigned short* __restrict__ Wt,   // 1024 x 1024 bf16 (Wo^T)
    const float* __restrict__ bo,
    float* __restrict__ Y) {
  constexpr int K = DIM;
  __shared__ unsigned short As[128 * 72];
  __shared__ unsigned short Bs[64 * 72];
  const int tid  = threadIdx.x;
  const int lane = tid & 63, wave = tid >> 6;
  const int l16  = lane & 15, quad = lane >> 4;
  const int wm   = wave * 32;                 // wave owns 32 rows, all 64 cols
  const int tm   = blockIdx.y * 128, tn = blockIdx.x * 64;
  const int srow = tid >> 3, scol = (tid & 7) * 8;

  floatx4 acc[2][4] = {};

  for (int k0 = 0; k0 < K; k0 += 64) {
    __syncthreads();
#pragma unroll
    for (int p = 0; p < 4; ++p) {
      const int row = srow + p * 32;
      *(ushortx8*)&As[row * 72 + scol] =
          *(const ushortx8*)&A[(size_t)(tm + row) * K + k0 + scol];
    }
#pragma unroll
    for (int p = 0; p < 2; ++p) {
      const int row = srow + p * 32;
      if (row < 64)
        *(ushortx8*)&Bs[row * 72 + scol] =
            *(const ushortx8*)&Wt[(size_t)(tn + row) * K + k0 + scol];
    }
    __syncthreads();
#pragma unroll
    for (int step = 0; step < 2; ++step) {
      const int kk = step * 32 + quad * 8;
      bf16x8 af[2], bfr[4];
#pragma unroll
      for (int i = 0; i < 2; ++i)
        af[i] = *(const bf16x8*)&As[(wm + i * 16 + l16) * 72 + kk];
#pragma unroll
      for (int j = 0; j < 4; ++j)
        bfr[j] = *(const bf16x8*)&Bs[(j * 16 + l16) * 72 + kk];
#pragma unroll
      for (int i = 0; i < 2; ++i)
#pragma unroll
        for (int j = 0; j < 4; ++j)
          acc[i][j] = __builtin_amdgcn_mfma_f32_16x16x32_bf16(af[i], bfr[j],
                                                              acc[i][j], 0, 0, 0);
    }
  }

#pragma unroll
  for (int j = 0; j < 4; ++j) {
    const int n = tn + j * 16 + l16;
    const float bias = bo[n];
#pragma unroll
    for (int i = 0; i < 2; ++i) {
      const int m0 = tm + wm + i * 16 + quad * 4;
#pragma unroll
      for (int r = 0; r < 4; ++r)
        Y[(size_t)(m0 + r) * DIM + n] = acc[i][j][r] + bias;
    }
  }
}

// ---------------------------------------------------------------------------
// Flash attention, barrier-free. 1 wave per block (64 thr), 32 qrows/wave.
// Grid: 2048 1D blocks, swizzled so a CU's co-resident blocks {c, c+256, ...}
// share one head: bh=(b>>3)&31, qt=(b>>8)*8+(b&7) -> K/V tiles reused in L1.
// Per 64-key tile: load all K (8) + V (8) bf16x8 fragments DIRECT from
// global; S^T = K Q^T; p = exp2(s'); P -> per-wave LDS (lgkmcnt drain, no
// barrier); O += P V. No __syncthreads anywhere.
// ---------------------------------------------------------------------------
__global__ __launch_bounds__(64) void attn_fwd(
    const unsigned short* __restrict__ Qb,
    const unsigned short* __restrict__ Kb,
    const unsigned short* __restrict__ VbT,
    unsigned short* __restrict__ ctx) {
  __shared__ unsigned short Pl[32 * 72];      // per-wave P [qrow 0..31][key]

  const int lane = threadIdx.x;               // 0..63
  const int l16  = lane & 15, quad = lane >> 4;
  const int b    = blockIdx.x;
  const int bh   = (b >> 3) & 31;
  const int qt   = ((b >> 8) << 3) | (b & 7);
  const size_t slab = (size_t)bh * SEQ * HDIM;
  const unsigned short* Q  = Qb + slab;
  const unsigned short* Kp = Kb + slab;
  const unsigned short* Vp = VbT + slab;      // [d][s] view, 64 x 2048
  const int q0 = qt * 32;

  // Q fragments (pre-scaled by QSCALE): B-operand, halves h=0,1
  bf16x8 qf[2][2];
#pragma unroll
  for (int h = 0; h < 2; ++h) {
    qf[h][0] = *(const bf16x8*)&Q[(size_t)(q0 + h * 16 + l16) * HDIM + quad * 8];
    qf[h][1] = *(const bf16x8*)&Q[(size_t)(q0 + h * 16 + l16) * HDIM + 32 + quad * 8];
  }

  floatx4 o[2][4] = {};
  float lr[2] = {0.f, 0.f};

  for (int kt = 0; kt < SEQ; kt += 64) {
    // All K and V fragments for this tile, direct from global (L1/L2-hot).
    // vf is consumed last -> its latency is covered by S + softmax.
    bf16x8 kf[2][4], vf[2][4];
#pragma unroll
    for (int step = 0; step < 2; ++step)
#pragma unroll
      for (int mt = 0; mt < 4; ++mt)
        kf[step][mt] = *(const bf16x8*)
            &Kp[(size_t)(kt + mt * 16 + l16) * HDIM + step * 32 + quad * 8];
#pragma unroll
    for (int step = 0; step < 2; ++step)
#pragma unroll
      for (int j = 0; j < 4; ++j)
        vf[step][j] = *(const bf16x8*)
            &Vp[((size_t)(j * 16 + l16) << 11) + kt + step * 32 + quad * 8];

    // S^T = K Q^T, both q-halves share each K fragment
    floatx4 s[2][4] = {};
#pragma unroll
    for (int step = 0; step < 2; ++step)
#pragma unroll
      for (int mt = 0; mt < 4; ++mt) {
        s[0][mt] = __builtin_amdgcn_mfma_f32_16x16x32_bf16(kf[step][mt], qf[0][step], s[0][mt], 0, 0, 0);
        s[1][mt] = __builtin_amdgcn_mfma_f32_16x16x32_bf16(kf[step][mt], qf[1][step], s[1][mt], 0, 0, 0);
      }

    // max-free softmax: p = exp2(s'), accumulate l per-lane, pack P -> LDS
#pragma unroll
    for (int h = 0; h < 2; ++h) {
#pragma unroll
      for (int mt = 0; mt < 4; ++mt) {
        float p0 = __builtin_amdgcn_exp2f(s[h][mt][0]);
        float p1 = __builtin_amdgcn_exp2f(s[h][mt][1]);
        float p2 = __builtin_amdgcn_exp2f(s[h][mt][2]);
        float p3 = __builtin_amdgcn_exp2f(s[h][mt][3]);
        lr[h] += (p0 + p1) + (p2 + p3);
        uint2 pv;
        pv.x = pk2bf(p0, p1);
        pv.y = pk2bf(p2, p3);
        *(uint2*)&Pl[(h * 16 + l16) * 72 + mt * 16 + quad * 4] = pv;
      }
    }
    // per-wave LDS RAW: drain ds queue; clobber stops compiler reordering
    __asm__ __volatile__("s_waitcnt lgkmcnt(0)" ::: "memory");

    // O += P V, both halves share each V fragment
#pragma unroll
    for (int step = 0; step < 2; ++step) {
      const int kk = step * 32 + quad * 8;
      bf16x8 pf0 = *(const bf16x8*)&Pl[(l16) * 72 + kk];
      bf16x8 pf1 = *(const bf16x8*)&Pl[(16 + l16) * 72 + kk];
#pragma unroll
      for (int j = 0; j < 4; ++j) {
        o[0][j] = __builtin_amdgcn_mfma_f32_16x16x32_bf16(pf0, vf[step][j], o[0][j], 0, 0, 0);
        o[1][j] = __builtin_amdgcn_mfma_f32_16x16x32_bf16(pf1, vf[step][j], o[1][j], 0, 0, 0);
      }
    }
  }

  // final l reduction (once): sum over the 4 quads holding each q-row
#pragma unroll
  for (int h = 0; h < 2; ++h) {
    lr[h] += __shfl_xor(lr[h], 16, 64);
    lr[h] += __shfl_xor(lr[h], 32, 64);
  }
  unsigned short* cp = ctx + slab;
#pragma unroll
  for (int h = 0; h < 2; ++h) {
    float lb[4];
#pragma unroll
    for (int r = 0; r < 4; ++r)
      lb[r] = 1.0f / __shfl(lr[h], quad * 4 + r, 64);
#pragma unroll
    for (int j = 0; j < 4; ++j)
#pragma unroll
      for (int r = 0; r < 4; ++r)
        cp[(size_t)(q0 + h * 16 + quad * 4 + r) * HDIM + j * 16 + l16] =
            f2bf(o[h][j][r] * lb[r]);
  }
}

// ---- residual + LayerNorm + exact GELU (erf), one block per row, float4 ----
__global__ __launch_bounds__(256) void ln_gelu(
    const float* __restrict__ x, const float* __restrict__ y,
    const float* __restrict__ gamma, const float* __restrict__ beta,
    float* __restrict__ out) {
  const int row = blockIdx.x;
  const int tid = threadIdx.x;
  const float4 xv = ((const float4*)(x + (size_t)row * DIM))[tid];
  const float4 yv = ((const float4*)(y + (size_t)row * DIM))[tid];
  float4 s;
  s.x = xv.x + yv.x; s.y = xv.y + yv.y; s.z = xv.z + yv.z; s.w = xv.w + yv.w;
  float sum = (s.x + s.y) + (s.z + s.w);
  float sq  = (s.x * s.x + s.y * s.y) + (s.z * s.z + s.w * s.w);
#pragma unroll
  for (int off = 1; off < 64; off <<= 1) {
    sum += __shfl_xor(sum, off, 64);
    sq  += __shfl_xor(sq, off, 64);
  }
  __shared__ float red[8];
  const int wave = tid >> 6, lane = tid & 63;
  if (lane == 0) { red[wave] = sum; red[wave + 4] = sq; }
  __syncthreads();
  sum = red[0] + red[1] + red[2] + red[3];
  sq  = red[4] + red[5] + red[6] + red[7];
  const float mu   = sum * (1.0f / DIM);
  const float var  = sq * (1.0f / DIM) - mu * mu;
  const float rstd = rsqrtf(var + 1e-5f);
  const float4 gv = ((const float4*)gamma)[tid];
  const float4 bv = ((const float4*)beta)[tid];
  float4 ov;
  {
    const float v = (s.x - mu) * rstd * gv.x + bv.x;
    ov.x = 0.5f * v * (1.0f + erff(v * 0.70710678118654752f));
  }
  {
    const float v = (s.y - mu) * rstd * gv.y + bv.y;
    ov.y = 0.5f * v * (1.0f + erff(v * 0.70710678118654752f));
  }
  {
    const float v = (s.z - mu) * rstd * gv.z + bv.z;
    ov.z = 0.5f * v * (1.0f + erff(v * 0.70710678118654752f));
  }
  {
    const float v = (s.w - mu) * rstd * gv.w + bv.w;
    ov.w = 0.5f * v * (1.0f + erff(v * 0.70710678118654752f));
  }
  ((float4*)(out + (size_t)row * DIM))[tid] = ov;
}

// ---------------------------------------------------------------------------
extern "C" void kernel_launch(void* const* d_in, const int* in_sizes, int n_in,
                              void* d_out, int out_size, void* d_ws, size_t ws_size,
                              hipStream_t stream) {
  (void)in_sizes; (void)n_in; (void)out_size; (void)ws_size;
  const float* x     = (const float*)d_in[0];
  const float* Wq    = (const float*)d_in[1];
  const float* bq    = (const float*)d_in[2];
  const float* Wk    = (const float*)d_in[3];
  const float* bk    = (const float*)d_in[4];
  const float* Wv    = (const float*)d_in[5];
  const float* bv    = (const float*)d_in[6];
  const float* Wo    = (const float*)d_in[7];
  const float* bo    = (const float*)d_in[8];
  const float* gamma = (const float*)d_in[9];
  const float* beta  = (const float*)d_in[10];
  float* out = (float*)d_out;

  char* ws = (char*)d_ws;
  const size_t MB = 1u << 20;
  unsigned short* xb    = (unsigned short*)(ws);             //  8 MB
  unsigned short* Wqkvt = (unsigned short*)(ws + 8 * MB);    //  6 MB
  unsigned short* Wot   = (unsigned short*)(ws + 14 * MB);   //  2 MB
  unsigned short* Qb    = (unsigned short*)(ws + 16 * MB);   //  8 MB
  unsigned short* Kb    = (unsigned short*)(ws + 24 * MB);   //  8 MB
  unsigned short* VbT   = (unsigned short*)(ws + 32 * MB);   //  8 MB (per-head transposed)
  unsigned short* Vb    = (unsigned short*)(ws + 40 * MB);   //  8 MB (dead after transpose_v)
  unsigned short* Cx    = (unsigned short*)(ws + 40 * MB);   //  8 MB (reuses Vb slot)
  float*          Y     = (float*)(ws + 48 * MB);            // 16 MB

  cvt_bf16<<<(ROWS * DIM / 4 + 255) / 256, 256, 0, stream>>>(x, xb, ROWS * DIM / 4);
  transpose_w4<<<dim3(32, 32, 4), dim3(32, 8), 0, stream>>>(Wq, Wk, Wv, Wo, Wqkvt, Wot);

  gemm_qkv<<<dim3(24, 32), 256, 0, stream>>>(xb, Wqkvt, bq, bk, bv, Qb, Kb, Vb);
  transpose_v<<<dim3(SEQ / 64, 32), dim3(64, 4), 0, stream>>>(Vb, VbT);
  attn_fwd<<<2048, 64, 0, stream>>>(Qb, Kb, VbT, Cx);
  gemm_o<<<dim3(16, 32), 256, 0, stream>>>(Cx, Wot, bo, Y);
  ln_gelu<<<ROWS, 256, 0, stream>>>(x, Y, gamma, beta, out);
}

// Round 10
// 228.295 us; speedup vs baseline: 1.3024x; 1.3024x over previous
//
#include <hip/hip_runtime.h>
#include <hip/hip_bf16.h>
#include <cstdint>
#include <cstddef>

// ---------------------------------------------------------------------------
// MultiheadSelfAttention fused pipeline for MI355X (gfx950)
// Head (b,h) = contiguous slab of the FLAT projection output (torch-faithful
// reshape without transpose): slab = (2048,64) row-major at bh*131072.
// Q pre-scaled by 0.125*log2(e) in gemm_qkv; max-free exp2 softmax.
// V transposed per head by transpose_v (slab view -> [d][s]).
// attn_fwd = round-8 proven version (72 us): LDS staging + register
// prefetch, 2-wave blocks. Round-9's direct-global fragment loads were a
// 16-line-splitting gather (hbm 1108->633 GB/s) — reverted.
// Round 10: GEMMs staged via __builtin_amdgcn_global_load_lds width=16
// (m93->m97 ladder step, 517->874 TF measured): unpadded LDS tiles,
// wave-uniform base + lane*16B (m104 semantics).
// ---------------------------------------------------------------------------

#define SEQ   2048
#define DIM   1024
#define NHEAD 16
#define HDIM  64
#define ROWS  4096   // B*S

#define QSCALE 0.1803368801111204f   // 0.125 * log2(e)

typedef __attribute__((ext_vector_type(8))) __bf16 bf16x8;
typedef __attribute__((ext_vector_type(4))) float floatx4;
typedef __attribute__((ext_vector_type(8))) unsigned short ushortx8;

__device__ __forceinline__ unsigned short f2bf(float f) {
  unsigned int u = __float_as_uint(f);
  u += 0x7FFFu + ((u >> 16) & 1u);   // round-to-nearest-even
  return (unsigned short)(u >> 16);
}

__device__ __forceinline__ unsigned int pk2bf(float a, float b) {
  float2 f; f.x = a; f.y = b;                       // x -> low 16
  __hip_bfloat162 h = __float22bfloat162_rn(f);
  return *(unsigned int*)&h;
}

// async global->LDS, 16B/lane; LDS dest = wave-uniform base + lane*16 (m104)
__device__ __forceinline__ void glds16(const unsigned short* g,
                                       unsigned short* l) {
  __builtin_amdgcn_global_load_lds(
      (const __attribute__((address_space(1))) void*)g,
      (__attribute__((address_space(3))) void*)l, 16, 0, 0);
}

// ---- fp32 -> bf16 elementwise convert (vectorized float4 -> 4x bf16) -------
__global__ __launch_bounds__(256) void cvt_bf16(const float* __restrict__ in,
                                                unsigned short* __restrict__ out,
                                                int n4) {
  int i = blockIdx.x * 256 + threadIdx.x;
  if (i >= n4) return;
  float4 v = ((const float4*)in)[i];
  ushort4 o;
  o.x = f2bf(v.x); o.y = f2bf(v.y); o.z = f2bf(v.z); o.w = f2bf(v.w);
  ((ushort4*)out)[i] = o;
}

// ---- 4x (1024x1024 fp32 -> transposed bf16), one launch (z = matrix) -------
__global__ __launch_bounds__(256) void transpose_w4(
    const float* __restrict__ Wq, const float* __restrict__ Wk,
    const float* __restrict__ Wv, const float* __restrict__ Wo,
    unsigned short* __restrict__ Wqkvt, unsigned short* __restrict__ Wot) {
  __shared__ float t[32][33];
  const int z = blockIdx.z;
  const float* in = (z == 0) ? Wq : (z == 1) ? Wk : (z == 2) ? Wv : Wo;
  unsigned short* out = (z < 3) ? Wqkvt + (size_t)z * DIM * DIM : Wot;
  const int bx = blockIdx.x * 32, by = blockIdx.y * 32;
  const int tx = threadIdx.x, ty = threadIdx.y;
#pragma unroll
  for (int i = ty; i < 32; i += 8)
    t[i][tx] = in[(size_t)(by + i) * DIM + bx + tx];
  __syncthreads();
#pragma unroll
  for (int i = ty; i < 32; i += 8)
    out[(size_t)(bx + i) * DIM + by + tx] = f2bf(t[tx][i]);
}

// ---- per-head V transpose: slab (2048,64) -> (64,2048), bh = 0..31 ---------
__global__ __launch_bounds__(256) void transpose_v(
    const unsigned short* __restrict__ Vb,   // flat: 32 slabs of 2048x64
    unsigned short* __restrict__ VbT) {      // 32 slabs of 64x2048
  __shared__ unsigned short t[64][65];
  const int bh = blockIdx.y;
  const int s0 = blockIdx.x * 64;
  const int tx = threadIdx.x;                // 0..63
  const int ty = threadIdx.y;                // 0..3
  const unsigned short* src = Vb + (size_t)bh * (SEQ * HDIM);
  unsigned short* dst = VbT + (size_t)bh * (SEQ * HDIM);
#pragma unroll
  for (int i = ty; i < 64; i += 4)
    t[i][tx] = src[(size_t)(s0 + i) * HDIM + tx];
  __syncthreads();
#pragma unroll
  for (int i = ty; i < 64; i += 4)
    dst[(size_t)i * SEQ + s0 + tx] = t[tx][i];
}

// ---------------------------------------------------------------------------
// Fused QKV GEMM, global_load_lds staging (m97 pattern). Unpadded LDS tiles
// (128x64 shorts, stride 64): glds inst q writes rows 8q..8q+7 contiguously.
// Q written PRE-SCALED by QSCALE (max-free exp2 softmax).
// ---------------------------------------------------------------------------
__global__ __launch_bounds__(256, 3) void gemm_qkv(
    const unsigned short* __restrict__ A,    // 4096 x 1024 bf16
    const unsigned short* __restrict__ Wt,   // 3072 x 1024 bf16
    const float* __restrict__ bq, const float* __restrict__ bk,
    const float* __restrict__ bv,
    unsigned short* __restrict__ Qb, unsigned short* __restrict__ Kb,
    unsigned short* __restrict__ Vb) {
  constexpr int K = DIM;
  __shared__ unsigned short As[128 * 64];    // unpadded (glds layout)
  __shared__ unsigned short Bs[128 * 64];
  const int tid  = threadIdx.x;
  const int lane = tid & 63, wave = tid >> 6;
  const int l16  = lane & 15, quad = lane >> 4;
  const int wm   = (wave & 1) * 64, wn = (wave >> 1) * 64;
  const int tm   = blockIdx.y * 128, tn = blockIdx.x * 128;
  const int grow = lane >> 3, gcol = (lane & 7) * 8;   // lane's 16B chunk

  floatx4 acc[4][4] = {};

  for (int k0 = 0; k0 < K; k0 += 64) {
    __syncthreads();
#pragma unroll
    for (int p = 0; p < 4; ++p) {
      const int q = wave * 4 + p;            // inst 0..15, rows 8q..8q+7
      const int row = q * 8 + grow;
      glds16(&A [(size_t)(tm + row) * K + k0 + gcol], &As[q * 512]);
      glds16(&Wt[(size_t)(tn + row) * K + k0 + gcol], &Bs[q * 512]);
    }
    __syncthreads();
#pragma unroll
    for (int step = 0; step < 2; ++step) {
      const int kk = step * 32 + quad * 8;
      bf16x8 af[4], bfr[4];
#pragma unroll
      for (int i = 0; i < 4; ++i)
        af[i] = *(const bf16x8*)&As[(wm + i * 16 + l16) * 64 + kk];
#pragma unroll
      for (int j = 0; j < 4; ++j)
        bfr[j] = *(const bf16x8*)&Bs[(wn + j * 16 + l16) * 64 + kk];
#pragma unroll
      for (int i = 0; i < 4; ++i)
#pragma unroll
        for (int j = 0; j < 4; ++j)
          acc[i][j] = __builtin_amdgcn_mfma_f32_16x16x32_bf16(af[i], bfr[j],
                                                              acc[i][j], 0, 0, 0);
    }
  }

#pragma unroll
  for (int j = 0; j < 4; ++j) {
    const int ng  = tn + wn + j * 16 + l16;   // output channel 0..3071
    const int seg = ng >> 10;                 // 0=Q 1=K 2=V
    const int col = ng & 1023;
    const float* bp    = (seg == 0) ? bq : (seg == 1) ? bk : bv;
    unsigned short* op = (seg == 0) ? Qb : (seg == 1) ? Kb : Vb;
    const float bias = bp[col];
    const float scl  = (seg == 0) ? QSCALE : 1.0f;
#pragma unroll
    for (int i = 0; i < 4; ++i) {
      const int m0 = tm + wm + i * 16 + quad * 4;
#pragma unroll
      for (int r = 0; r < 4; ++r)
        op[(size_t)(m0 + r) * DIM + col] = f2bf((acc[i][j][r] + bias) * scl);
    }
  }
}

// ---- Output projection GEMM: Y = ctx @ Wo + bo. 128x64 tiles (512 blocks =
// 2/CU), global_load_lds staging. ---------------------------------------------
__global__ __launch_bounds__(256) void gemm_o(
    const unsigned short* __restrict__ A,    // 4096 x 1024 bf16 (ctx)
    const unsigned short* __restrict__ Wt,   // 1024 x 1024 bf16 (Wo^T)
    const float* __restrict__ bo,
    float* __restrict__ Y) {
  constexpr int K = DIM;
  __shared__ unsigned short As[128 * 64];    // unpadded (glds layout)
  __shared__ unsigned short Bs[64 * 64];
  const int tid  = threadIdx.x;
  const int lane = tid & 63, wave = tid >> 6;
  const int l16  = lane & 15, quad = lane >> 4;
  const int wm   = wave * 32;                 // wave owns 32 rows, all 64 cols
  const int tm   = blockIdx.y * 128, tn = blockIdx.x * 64;
  const int grow = lane >> 3, gcol = (lane & 7) * 8;

  floatx4 acc[2][4] = {};

  for (int k0 = 0; k0 < K; k0 += 64) {
    __syncthreads();
#pragma unroll
    for (int p = 0; p < 4; ++p) {
      const int q = wave * 4 + p;            // 0..15
      const int row = q * 8 + grow;
      glds16(&A[(size_t)(tm + row) * K + k0 + gcol], &As[q * 512]);
    }
#pragma unroll
    for (int p = 0; p < 2; ++p) {
      const int q = wave * 2 + p;            // 0..7
      const int row = q * 8 + grow;
      glds16(&Wt[(size_t)(tn + row) * K + k0 + gcol], &Bs[q * 512]);
    }
    __syncthreads();
#pragma unroll
    for (int step = 0; step < 2; ++step) {
      const int kk = step * 32 + quad * 8;
      bf16x8 af[2], bfr[4];
#pragma unroll
      for (int i = 0; i < 2; ++i)
        af[i] = *(const bf16x8*)&As[(wm + i * 16 + l16) * 64 + kk];
#pragma unroll
      for (int j = 0; j < 4; ++j)
        bfr[j] = *(const bf16x8*)&Bs[(j * 16 + l16) * 64 + kk];
#pragma unroll
      for (int i = 0; i < 2; ++i)
#pragma unroll
        for (int j = 0; j < 4; ++j)
          acc[i][j] = __builtin_amdgcn_mfma_f32_16x16x32_bf16(af[i], bfr[j],
                                                              acc[i][j], 0, 0, 0);
    }
  }

#pragma unroll
  for (int j = 0; j < 4; ++j) {
    const int n = tn + j * 16 + l16;
    const float bias = bo[n];
#pragma unroll
    for (int i = 0; i < 2; ++i) {
      const int m0 = tm + wm + i * 16 + quad * 4;
#pragma unroll
      for (int r = 0; r < 4; ++r)
        Y[(size_t)(m0 + r) * DIM + n] = acc[i][j][r] + bias;
    }
  }
}

// ---------------------------------------------------------------------------
// Flash attention — round-8 proven version (72 us). S^T formulation, max-free
// exp2 softmax, 32 qrows/wave, 2 waves/block (64 qrows/block). grid
// (SEQ/64, B*NHEAD) = 1024 blocks = 4 blocks/CU. Next K/V tile prefetched
// into registers during compute. LDS: Kl 9216 + Vt 9216 + Pl 9216 = 27648 B.
// ---------------------------------------------------------------------------
__global__ __launch_bounds__(128, 2) void attn_fwd(
    const unsigned short* __restrict__ Qb,
    const unsigned short* __restrict__ Kb,
    const unsigned short* __restrict__ VbT,
    unsigned short* __restrict__ ctx) {
  __shared__ unsigned short Kl[64 * 72];      // [key][k]
  __shared__ unsigned short Vt[64 * 72];      // [d][key]
  __shared__ unsigned short Pl[2][32 * 72];   // per-wave P [qrow 0..31][key]

  const int tid  = threadIdx.x;               // 0..127
  const int lane = tid & 63, wave = tid >> 6; // wave 0..1
  const int l16  = lane & 15, quad = lane >> 4;
  const size_t slab = (size_t)blockIdx.y * SEQ * HDIM;
  const unsigned short* Q  = Qb + slab;
  const unsigned short* Kp = Kb + slab;
  const unsigned short* Vp = VbT + slab;      // [d][s] view
  const int q0 = blockIdx.x * 64 + wave * 32;

  // Q fragments (pre-scaled by QSCALE): B-operand, halves h=0,1
  bf16x8 qf[2][2];
#pragma unroll
  for (int h = 0; h < 2; ++h) {
    qf[h][0] = *(const bf16x8*)&Q[(size_t)(q0 + h * 16 + l16) * HDIM + quad * 8];
    qf[h][1] = *(const bf16x8*)&Q[(size_t)(q0 + h * 16 + l16) * HDIM + 32 + quad * 8];
  }

  floatx4 o[2][4] = {};
  float lr[2] = {0.f, 0.f};

  // staging map: 512 chunks of 8 shorts per tile, 4 chunks/thread each of K,V
  ushortx8 kr[4], vr[4];
#pragma unroll
  for (int p = 0; p < 4; ++p) {
    const int c = p * 128 + tid;
    const int row = c >> 3, col = (c & 7) * 8;
    kr[p] = *(const ushortx8*)&Kp[(size_t)row * HDIM + col];
    vr[p] = *(const ushortx8*)&Vp[((size_t)row << 11) + col];
  }

  for (int kt = 0; kt < SEQ; kt += 64) {
    __syncthreads();                          // prev iter's LDS readers done
#pragma unroll
    for (int p = 0; p < 4; ++p) {
      const int c = p * 128 + tid;
      const int row = c >> 3, col = (c & 7) * 8;
      *(ushortx8*)&Kl[row * 72 + col] = kr[p];
      *(ushortx8*)&Vt[row * 72 + col] = vr[p];
    }
    __syncthreads();

    // prefetch next tile into registers (overlaps with compute below)
    if (kt + 64 < SEQ) {
#pragma unroll
      for (int p = 0; p < 4; ++p) {
        const int c = p * 128 + tid;
        const int row = c >> 3, col = (c & 7) * 8;
        kr[p] = *(const ushortx8*)&Kp[(size_t)(kt + 64 + row) * HDIM + col];
        vr[p] = *(const ushortx8*)&Vp[((size_t)row << 11) + kt + 64 + col];
      }
    }

    // S^T = K Q^T, both q-halves share each K fragment
    floatx4 s[2][4] = {};
#pragma unroll
    for (int step = 0; step < 2; ++step) {
      const int kk = step * 32 + quad * 8;
#pragma unroll
      for (int mt = 0; mt < 4; ++mt) {
        bf16x8 kfr = *(const bf16x8*)&Kl[(mt * 16 + l16) * 72 + kk];
        s[0][mt] = __builtin_amdgcn_mfma_f32_16x16x32_bf16(kfr, qf[0][step], s[0][mt], 0, 0, 0);
        s[1][mt] = __builtin_amdgcn_mfma_f32_16x16x32_bf16(kfr, qf[1][step], s[1][mt], 0, 0, 0);
      }
    }

    // max-free softmax: p = exp2(s'), accumulate l per-lane, pack P -> LDS
#pragma unroll
    for (int h = 0; h < 2; ++h) {
#pragma unroll
      for (int mt = 0; mt < 4; ++mt) {
        float p0 = __builtin_amdgcn_exp2f(s[h][mt][0]);
        float p1 = __builtin_amdgcn_exp2f(s[h][mt][1]);
        float p2 = __builtin_amdgcn_exp2f(s[h][mt][2]);
        float p3 = __builtin_amdgcn_exp2f(s[h][mt][3]);
        lr[h] += (p0 + p1) + (p2 + p3);
        uint2 pv;
        pv.x = pk2bf(p0, p1);
        pv.y = pk2bf(p2, p3);
        *(uint2*)&Pl[wave][(h * 16 + l16) * 72 + mt * 16 + quad * 4] = pv;
      }
    }
    // per-wave LDS RAW: drain ds queue; clobber stops compiler reordering
    __asm__ __volatile__("s_waitcnt lgkmcnt(0)" ::: "memory");

    // O += P V, both halves share each V fragment
#pragma unroll
    for (int step = 0; step < 2; ++step) {
      const int kk = step * 32 + quad * 8;
      bf16x8 pf0 = *(const bf16x8*)&Pl[wave][(l16) * 72 + kk];
      bf16x8 pf1 = *(const bf16x8*)&Pl[wave][(16 + l16) * 72 + kk];
#pragma unroll
      for (int j = 0; j < 4; ++j) {
        bf16x8 vf = *(const bf16x8*)&Vt[(j * 16 + l16) * 72 + kk];
        o[0][j] = __builtin_amdgcn_mfma_f32_16x16x32_bf16(pf0, vf, o[0][j], 0, 0, 0);
        o[1][j] = __builtin_amdgcn_mfma_f32_16x16x32_bf16(pf1, vf, o[1][j], 0, 0, 0);
      }
    }
  }

  // final l reduction (once): sum over the 4 quads holding each q-row
#pragma unroll
  for (int h = 0; h < 2; ++h) {
    lr[h] += __shfl_xor(lr[h], 16, 64);
    lr[h] += __shfl_xor(lr[h], 32, 64);
  }
  unsigned short* cp = ctx + slab;
#pragma unroll
  for (int h = 0; h < 2; ++h) {
    float lb[4];
#pragma unroll
    for (int r = 0; r < 4; ++r)
      lb[r] = 1.0f / __shfl(lr[h], quad * 4 + r, 64);
#pragma unroll
    for (int j = 0; j < 4; ++j)
#pragma unroll
      for (int r = 0; r < 4; ++r)
        cp[(size_t)(q0 + h * 16 + quad * 4 + r) * HDIM + j * 16 + l16] =
            f2bf(o[h][j][r] * lb[r]);
  }
}

// ---- residual + LayerNorm + exact GELU (erf), one block per row, float4 ----
__global__ __launch_bounds__(256) void ln_gelu(
    const float* __restrict__ x, const float* __restrict__ y,
    const float* __restrict__ gamma, const float* __restrict__ beta,
    float* __restrict__ out) {
  const int row = blockIdx.x;
  const int tid = threadIdx.x;
  const float4 xv = ((const float4*)(x + (size_t)row * DIM))[tid];
  const float4 yv = ((const float4*)(y + (size_t)row * DIM))[tid];
  float4 s;
  s.x = xv.x + yv.x; s.y = xv.y + yv.y; s.z = xv.z + yv.z; s.w = xv.w + yv.w;
  float sum = (s.x + s.y) + (s.z + s.w);
  float sq  = (s.x * s.x + s.y * s.y) + (s.z * s.z + s.w * s.w);
#pragma unroll
  for (int off = 1; off < 64; off <<= 1) {
    sum += __shfl_xor(sum, off, 64);
    sq  += __shfl_xor(sq, off, 64);
  }
  __shared__ float red[8];
  const int wave = tid >> 6, lane = tid & 63;
  if (lane == 0) { red[wave] = sum; red[wave + 4] = sq; }
  __syncthreads();
  sum = red[0] + red[1] + red[2] + red[3];
  sq  = red[4] + red[5] + red[6] + red[7];
  const float mu   = sum * (1.0f / DIM);
  const float var  = sq * (1.0f / DIM) - mu * mu;
  const float rstd = rsqrtf(var + 1e-5f);
  const float4 gv = ((const float4*)gamma)[tid];
  const float4 bv = ((const float4*)beta)[tid];
  float4 ov;
  {
    const float v = (s.x - mu) * rstd * gv.x + bv.x;
    ov.x = 0.5f * v * (1.0f + erff(v * 0.70710678118654752f));
  }
  {
    const float v = (s.y - mu) * rstd * gv.y + bv.y;
    ov.y = 0.5f * v * (1.0f + erff(v * 0.70710678118654752f));
  }
  {
    const float v = (s.z - mu) * rstd * gv.z + bv.z;
    ov.z = 0.5f * v * (1.0f + erff(v * 0.70710678118654752f));
  }
  {
    const float v = (s.w - mu) * rstd * gv.w + bv.w;
    ov.w = 0.5f * v * (1.0f + erff(v * 0.70710678118654752f));
  }
  ((float4*)(out + (size_t)row * DIM))[tid] = ov;
}

// ---------------------------------------------------------------------------
extern "C" void kernel_launch(void* const* d_in, const int* in_sizes, int n_in,
                              void* d_out, int out_size, void* d_ws, size_t ws_size,
                              hipStream_t stream) {
  (void)in_sizes; (void)n_in; (void)out_size; (void)ws_size;
  const float* x     = (const float*)d_in[0];
  const float* Wq    = (const float*)d_in[1];
  const float* bq    = (const float*)d_in[2];
  const float* Wk    = (const float*)d_in[3];
  const float* bk    = (const float*)d_in[4];
  const float* Wv    = (const float*)d_in[5];
  const float* bv    = (const float*)d_in[6];
  const float* Wo    = (const float*)d_in[7];
  const float* bo    = (const float*)d_in[8];
  const float* gamma = (const float*)d_in[9];
  const float* beta  = (const float*)d_in[10];
  float* out = (float*)d_out;

  char* ws = (char*)d_ws;
  const size_t MB = 1u << 20;
  unsigned short* xb    = (unsigned short*)(ws);             //  8 MB
  unsigned short* Wqkvt = (unsigned short*)(ws + 8 * MB);    //  6 MB
  unsigned short* Wot   = (unsigned short*)(ws + 14 * MB);   //  2 MB
  unsigned short* Qb    = (unsigned short*)(ws + 16 * MB);   //  8 MB
  unsigned short* Kb    = (unsigned short*)(ws + 24 * MB);   //  8 MB
  unsigned short* VbT   = (unsigned short*)(ws + 32 * MB);   //  8 MB (per-head transposed)
  unsigned short* Vb    = (unsigned short*)(ws + 40 * MB);   //  8 MB (dead after transpose_v)
  unsigned short* Cx    = (unsigned short*)(ws + 40 * MB);   //  8 MB (reuses Vb slot)
  float*          Y     = (float*)(ws + 48 * MB);            // 16 MB

  cvt_bf16<<<(ROWS * DIM / 4 + 255) / 256, 256, 0, stream>>>(x, xb, ROWS * DIM / 4);
  transpose_w4<<<dim3(32, 32, 4), dim3(32, 8), 0, stream>>>(Wq, Wk, Wv, Wo, Wqkvt, Wot);

  gemm_qkv<<<dim3(24, 32), 256, 0, stream>>>(xb, Wqkvt, bq, bk, bv, Qb, Kb, Vb);
  transpose_v<<<dim3(SEQ / 64, 32), dim3(64, 4), 0, stream>>>(Vb, VbT);
  attn_fwd<<<dim3(32, 32), 128, 0, stream>>>(Qb, Kb, VbT, Cx);
  gemm_o<<<dim3(16, 32), 256, 0, stream>>>(Cx, Wot, bo, Y);
  ln_gelu<<<ROWS, 256, 0, stream>>>(x, Y, gamma, beta, out);
}

// Round 11
// 227.160 us; speedup vs baseline: 1.3089x; 1.0050x over previous
//
#include <hip/hip_runtime.h>
#include <hip/hip_bf16.h>
#include <cstdint>
#include <cstddef>

// ---------------------------------------------------------------------------
// MultiheadSelfAttention fused pipeline for MI355X (gfx950)
// Head (b,h) = contiguous slab of the FLAT projection output (torch-faithful
// reshape without transpose): slab = (2048,64) row-major at bh*131072.
// Q pre-scaled by 0.125*log2(e) in gemm_qkv; max-free exp2 softmax.
// Round 11: K and V^T are SWIZZLED into MFMA-fragment-major layout
// (frag = 64 lanes x 16B contiguous) so attention loads every fragment as a
// coalesced 1KB global_load_dwordx4 — no K/V LDS staging, NO barriers.
// (R9 showed direct loads fail only due to the 16-line gather; R10 showed
// the LDS pipe at ~66% busy was the bottleneck. This fixes the layout.)
// Only the per-wave P round-trip (4.6KB) stays in LDS.
// ---------------------------------------------------------------------------

#define SEQ   2048
#define DIM   1024
#define NHEAD 16
#define HDIM  64
#define ROWS  4096   // B*S

#define QSCALE 0.1803368801111204f   // 0.125 * log2(e)

typedef __attribute__((ext_vector_type(8))) __bf16 bf16x8;
typedef __attribute__((ext_vector_type(4))) float floatx4;
typedef __attribute__((ext_vector_type(8))) unsigned short ushortx8;

__device__ __forceinline__ unsigned short f2bf(float f) {
  unsigned int u = __float_as_uint(f);
  u += 0x7FFFu + ((u >> 16) & 1u);   // round-to-nearest-even
  return (unsigned short)(u >> 16);
}

__device__ __forceinline__ unsigned int pk2bf(float a, float b) {
  float2 f; f.x = a; f.y = b;                       // x -> low 16
  __hip_bfloat162 h = __float22bfloat162_rn(f);
  return *(unsigned int*)&h;
}

// async global->LDS, 16B/lane; LDS dest = wave-uniform base + lane*16 (m104)
__device__ __forceinline__ void glds16(const unsigned short* g,
                                       unsigned short* l) {
  __builtin_amdgcn_global_load_lds(
      (const __attribute__((address_space(1))) void*)g,
      (__attribute__((address_space(3))) void*)l, 16, 0, 0);
}

// ---- fp32 -> bf16 elementwise convert (vectorized float4 -> 4x bf16) -------
__global__ __launch_bounds__(256) void cvt_bf16(const float* __restrict__ in,
                                                unsigned short* __restrict__ out,
                                                int n4) {
  int i = blockIdx.x * 256 + threadIdx.x;
  if (i >= n4) return;
  float4 v = ((const float4*)in)[i];
  ushort4 o;
  o.x = f2bf(v.x); o.y = f2bf(v.y); o.z = f2bf(v.z); o.w = f2bf(v.w);
  ((ushort4*)out)[i] = o;
}

// ---- 4x (1024x1024 fp32 -> transposed bf16), one launch (z = matrix) -------
__global__ __launch_bounds__(256) void transpose_w4(
    const float* __restrict__ Wq, const float* __restrict__ Wk,
    const float* __restrict__ Wv, const float* __restrict__ Wo,
    unsigned short* __restrict__ Wqkvt, unsigned short* __restrict__ Wot) {
  __shared__ float t[32][33];
  const int z = blockIdx.z;
  const float* in = (z == 0) ? Wq : (z == 1) ? Wk : (z == 2) ? Wv : Wo;
  unsigned short* out = (z < 3) ? Wqkvt + (size_t)z * DIM * DIM : Wot;
  const int bx = blockIdx.x * 32, by = blockIdx.y * 32;
  const int tx = threadIdx.x, ty = threadIdx.y;
#pragma unroll
  for (int i = ty; i < 32; i += 8)
    t[i][tx] = in[(size_t)(by + i) * DIM + bx + tx];
  __syncthreads();
#pragma unroll
  for (int i = ty; i < 32; i += 8)
    out[(size_t)(bx + i) * DIM + by + tx] = f2bf(t[tx][i]);
}

// ---- per-head V transpose: slab (2048,64) -> (64,2048), bh = 0..31 ---------
__global__ __launch_bounds__(256) void transpose_v(
    const unsigned short* __restrict__ Vb,   // flat: 32 slabs of 2048x64
    unsigned short* __restrict__ VbT) {      // 32 slabs of 64x2048
  __shared__ unsigned short t[64][65];
  const int bh = blockIdx.y;
  const int s0 = blockIdx.x * 64;
  const int tx = threadIdx.x;                // 0..63
  const int ty = threadIdx.y;                // 0..3
  const unsigned short* src = Vb + (size_t)bh * (SEQ * HDIM);
  unsigned short* dst = VbT + (size_t)bh * (SEQ * HDIM);
#pragma unroll
  for (int i = ty; i < 64; i += 4)
    t[i][tx] = src[(size_t)(s0 + i) * HDIM + tx];
  __syncthreads();
#pragma unroll
  for (int i = ty; i < 64; i += 4)
    dst[(size_t)i * SEQ + s0 + tx] = t[tx][i];
}

// ---- swizzle K (in-place) and V^T into fragment-major layout ----------------
// Per (tile, bh): frag f = step*4+g holds 64 lanes x 8 shorts contiguous:
//   K:  frag[lane] = K[kt + g*16+l16][step*32+quad*8 ..+7]
//   V:  frag[lane] = V^T[g*16+l16][kt + step*32+quad*8 ..+7]
// K's source tile (64 rows x 64 shorts, row stride 64) is CONTIGUOUS 8KB at
// the same offset as the dest tile -> safe in-place permutation via LDS.
__global__ __launch_bounds__(256) void swizzle_kv(
    unsigned short* __restrict__ Kb,         // in/out (in-place)
    const unsigned short* __restrict__ VbT,  // in
    unsigned short* __restrict__ Vs) {       // out
  __shared__ unsigned short t[64 * 72];
  const int tile = blockIdx.x;               // 0..31 (key tile)
  const int bh   = blockIdx.y;               // 0..31
  const int isV  = blockIdx.z;
  const int tid  = threadIdx.x;
  const size_t slab = (size_t)bh * (SEQ * HDIM);
  if (!isV) {
    const unsigned short* src = Kb + slab + (size_t)tile * 4096;  // 8KB contig
#pragma unroll
    for (int p = 0; p < 2; ++p) {
      const int c = p * 256 + tid;
      const int row = c >> 3, col = (c & 7) * 8;
      *(ushortx8*)&t[row * 72 + col] = *(const ushortx8*)&src[c * 8];
    }
  } else {
    const unsigned short* src = VbT + slab;
#pragma unroll
    for (int p = 0; p < 2; ++p) {
      const int c = p * 256 + tid;
      const int row = c >> 3, col = (c & 7) * 8;   // row = d
      *(ushortx8*)&t[row * 72 + col] =
          *(const ushortx8*)&src[(size_t)row * SEQ + tile * 64 + col];
    }
  }
  __syncthreads();
  unsigned short* dst = (isV ? Vs : Kb) + slab + (size_t)tile * 4096;
  const int lane = tid & 63, wave = tid >> 6;
  const int l16 = lane & 15, quad = lane >> 4;
#pragma unroll
  for (int f = wave * 2; f < wave * 2 + 2; ++f) {
    const int step = f >> 2, g = f & 3;
    *(ushortx8*)&dst[f * 512 + lane * 8] =
        *(const ushortx8*)&t[(g * 16 + l16) * 72 + step * 32 + quad * 8];
  }
}

// ---------------------------------------------------------------------------
// Fused QKV GEMM, global_load_lds staging (m97 pattern). Unpadded LDS tiles.
// Q written PRE-SCALED by QSCALE (max-free exp2 softmax).
// ---------------------------------------------------------------------------
__global__ __launch_bounds__(256, 3) void gemm_qkv(
    const unsigned short* __restrict__ A,    // 4096 x 1024 bf16
    const unsigned short* __restrict__ Wt,   // 3072 x 1024 bf16
    const float* __restrict__ bq, const float* __restrict__ bk,
    const float* __restrict__ bv,
    unsigned short* __restrict__ Qb, unsigned short* __restrict__ Kb,
    unsigned short* __restrict__ Vb) {
  constexpr int K = DIM;
  __shared__ unsigned short As[128 * 64];    // unpadded (glds layout)
  __shared__ unsigned short Bs[128 * 64];
  const int tid  = threadIdx.x;
  const int lane = tid & 63, wave = tid >> 6;
  const int l16  = lane & 15, quad = lane >> 4;
  const int wm   = (wave & 1) * 64, wn = (wave >> 1) * 64;
  const int tm   = blockIdx.y * 128, tn = blockIdx.x * 128;
  const int grow = lane >> 3, gcol = (lane & 7) * 8;   // lane's 16B chunk

  floatx4 acc[4][4] = {};

  for (int k0 = 0; k0 < K; k0 += 64) {
    __syncthreads();
#pragma unroll
    for (int p = 0; p < 4; ++p) {
      const int q = wave * 4 + p;            // inst 0..15, rows 8q..8q+7
      const int row = q * 8 + grow;
      glds16(&A [(size_t)(tm + row) * K + k0 + gcol], &As[q * 512]);
      glds16(&Wt[(size_t)(tn + row) * K + k0 + gcol], &Bs[q * 512]);
    }
    __syncthreads();
#pragma unroll
    for (int step = 0; step < 2; ++step) {
      const int kk = step * 32 + quad * 8;
      bf16x8 af[4], bfr[4];
#pragma unroll
      for (int i = 0; i < 4; ++i)
        af[i] = *(const bf16x8*)&As[(wm + i * 16 + l16) * 64 + kk];
#pragma unroll
      for (int j = 0; j < 4; ++j)
        bfr[j] = *(const bf16x8*)&Bs[(wn + j * 16 + l16) * 64 + kk];
#pragma unroll
      for (int i = 0; i < 4; ++i)
#pragma unroll
        for (int j = 0; j < 4; ++j)
          acc[i][j] = __builtin_amdgcn_mfma_f32_16x16x32_bf16(af[i], bfr[j],
                                                              acc[i][j], 0, 0, 0);
    }
  }

#pragma unroll
  for (int j = 0; j < 4; ++j) {
    const int ng  = tn + wn + j * 16 + l16;   // output channel 0..3071
    const int seg = ng >> 10;                 // 0=Q 1=K 2=V
    const int col = ng & 1023;
    const float* bp    = (seg == 0) ? bq : (seg == 1) ? bk : bv;
    unsigned short* op = (seg == 0) ? Qb : (seg == 1) ? Kb : Vb;
    const float bias = bp[col];
    const float scl  = (seg == 0) ? QSCALE : 1.0f;
#pragma unroll
    for (int i = 0; i < 4; ++i) {
      const int m0 = tm + wm + i * 16 + quad * 4;
#pragma unroll
      for (int r = 0; r < 4; ++r)
        op[(size_t)(m0 + r) * DIM + col] = f2bf((acc[i][j][r] + bias) * scl);
    }
  }
}

// ---- Output projection GEMM: Y = ctx @ Wo + bo. 128x64 tiles (512 blocks),
// global_load_lds staging. ----------------------------------------------------
__global__ __launch_bounds__(256) void gemm_o(
    const unsigned short* __restrict__ A,    // 4096 x 1024 bf16 (ctx)
    const unsigned short* __restrict__ Wt,   // 1024 x 1024 bf16 (Wo^T)
    const float* __restrict__ bo,
    float* __restrict__ Y) {
  constexpr int K = DIM;
  __shared__ unsigned short As[128 * 64];    // unpadded (glds layout)
  __shared__ unsigned short Bs[64 * 64];
  const int tid  = threadIdx.x;
  const int lane = tid & 63, wave = tid >> 6;
  const int l16  = lane & 15, quad = lane >> 4;
  const int wm   = wave * 32;                 // wave owns 32 rows, all 64 cols
  const int tm   = blockIdx.y * 128, tn = blockIdx.x * 64;
  const int grow = lane >> 3, gcol = (lane & 7) * 8;

  floatx4 acc[2][4] = {};

  for (int k0 = 0; k0 < K; k0 += 64) {
    __syncthreads();
#pragma unroll
    for (int p = 0; p < 4; ++p) {
      const int q = wave * 4 + p;            // 0..15
      const int row = q * 8 + grow;
      glds16(&A[(size_t)(tm + row) * K + k0 + gcol], &As[q * 512]);
    }
#pragma unroll
    for (int p = 0; p < 2; ++p) {
      const int q = wave * 2 + p;            // 0..7
      const int row = q * 8 + grow;
      glds16(&Wt[(size_t)(tn + row) * K + k0 + gcol], &Bs[q * 512]);
    }
    __syncthreads();
#pragma unroll
    for (int step = 0; step < 2; ++step) {
      const int kk = step * 32 + quad * 8;
      bf16x8 af[2], bfr[4];
#pragma unroll
      for (int i = 0; i < 2; ++i)
        af[i] = *(const bf16x8*)&As[(wm + i * 16 + l16) * 64 + kk];
#pragma unroll
      for (int j = 0; j < 4; ++j)
        bfr[j] = *(const bf16x8*)&Bs[(j * 16 + l16) * 64 + kk];
#pragma unroll
      for (int i = 0; i < 2; ++i)
#pragma unroll
        for (int j = 0; j < 4; ++j)
          acc[i][j] = __builtin_amdgcn_mfma_f32_16x16x32_bf16(af[i], bfr[j],
                                                              acc[i][j], 0, 0, 0);
    }
  }

#pragma unroll
  for (int j = 0; j < 4; ++j) {
    const int n = tn + j * 16 + l16;
    const float bias = bo[n];
#pragma unroll
    for (int i = 0; i < 2; ++i) {
      const int m0 = tm + wm + i * 16 + quad * 4;
#pragma unroll
      for (int r = 0; r < 4; ++r)
        Y[(size_t)(m0 + r) * DIM + n] = acc[i][j][r] + bias;
    }
  }
}

// ---------------------------------------------------------------------------
// Flash attention, BARRIER-FREE. S^T formulation, max-free exp2 softmax,
// 32 qrows/wave, 2 waves/block. K/V fragments loaded direct from the
// swizzled buffers as coalesced 1KB global_load_dwordx4 (both waves read the
// same lines -> L1 reuse). Only per-wave P round-trip in LDS (9216 B).
// grid (SEQ/64, B*NHEAD) = 1024 blocks = 4 blocks/CU.
// ---------------------------------------------------------------------------
__global__ __launch_bounds__(128) void attn_fwd(
    const unsigned short* __restrict__ Qb,
    const unsigned short* __restrict__ Ks,   // fragment-major K
    const unsigned short* __restrict__ Vs,   // fragment-major V^T
    unsigned short* __restrict__ ctx) {
  __shared__ unsigned short Pl[2][32 * 72];   // per-wave P [qrow 0..31][key]

  const int tid  = threadIdx.x;               // 0..127
  const int lane = tid & 63, wave = tid >> 6; // wave 0..1
  const int l16  = lane & 15, quad = lane >> 4;
  const size_t slab = (size_t)blockIdx.y * SEQ * HDIM;
  const unsigned short* Q  = Qb + slab;
  const unsigned short* Kf = Ks + slab;
  const unsigned short* Vf = Vs + slab;
  const int q0 = blockIdx.x * 64 + wave * 32;

  // Q fragments (pre-scaled by QSCALE): B-operand, halves h=0,1
  bf16x8 qf[2][2];
#pragma unroll
  for (int h = 0; h < 2; ++h) {
    qf[h][0] = *(const bf16x8*)&Q[(size_t)(q0 + h * 16 + l16) * HDIM + quad * 8];
    qf[h][1] = *(const bf16x8*)&Q[(size_t)(q0 + h * 16 + l16) * HDIM + 32 + quad * 8];
  }

  floatx4 o[2][4] = {};
  float lr[2] = {0.f, 0.f};

  for (int tile = 0; tile < SEQ / 64; ++tile) {
    const unsigned short* kb = Kf + (size_t)tile * 4096;
    const unsigned short* vb = Vf + (size_t)tile * 4096;
    bf16x8 kf[2][4], vf[2][4];
#pragma unroll
    for (int step = 0; step < 2; ++step)
#pragma unroll
      for (int g = 0; g < 4; ++g) {
        kf[step][g] = *(const bf16x8*)&kb[(step * 4 + g) * 512 + lane * 8];
        vf[step][g] = *(const bf16x8*)&vb[(step * 4 + g) * 512 + lane * 8];
      }

    // S^T = K Q^T, both q-halves share each K fragment
    floatx4 s[2][4] = {};
#pragma unroll
    for (int step = 0; step < 2; ++step)
#pragma unroll
      for (int mt = 0; mt < 4; ++mt) {
        s[0][mt] = __builtin_amdgcn_mfma_f32_16x16x32_bf16(kf[step][mt], qf[0][step], s[0][mt], 0, 0, 0);
        s[1][mt] = __builtin_amdgcn_mfma_f32_16x16x32_bf16(kf[step][mt], qf[1][step], s[1][mt], 0, 0, 0);
      }

    // max-free softmax: p = exp2(s'), accumulate l per-lane, pack P -> LDS
#pragma unroll
    for (int h = 0; h < 2; ++h) {
#pragma unroll
      for (int mt = 0; mt < 4; ++mt) {
        float p0 = __builtin_amdgcn_exp2f(s[h][mt][0]);
        float p1 = __builtin_amdgcn_exp2f(s[h][mt][1]);
        float p2 = __builtin_amdgcn_exp2f(s[h][mt][2]);
        float p3 = __builtin_amdgcn_exp2f(s[h][mt][3]);
        lr[h] += (p0 + p1) + (p2 + p3);
        uint2 pv;
        pv.x = pk2bf(p0, p1);
        pv.y = pk2bf(p2, p3);
        *(uint2*)&Pl[wave][(h * 16 + l16) * 72 + mt * 16 + quad * 4] = pv;
      }
    }
    // per-wave LDS RAW: drain ds queue; clobber stops compiler reordering
    __asm__ __volatile__("s_waitcnt lgkmcnt(0)" ::: "memory");

    // O += P V, both halves share each V fragment
#pragma unroll
    for (int step = 0; step < 2; ++step) {
      const int kk = step * 32 + quad * 8;
      bf16x8 pf0 = *(const bf16x8*)&Pl[wave][(l16) * 72 + kk];
      bf16x8 pf1 = *(const bf16x8*)&Pl[wave][(16 + l16) * 72 + kk];
#pragma unroll
      for (int j = 0; j < 4; ++j) {
        o[0][j] = __builtin_amdgcn_mfma_f32_16x16x32_bf16(pf0, vf[step][j], o[0][j], 0, 0, 0);
        o[1][j] = __builtin_amdgcn_mfma_f32_16x16x32_bf16(pf1, vf[step][j], o[1][j], 0, 0, 0);
      }
    }
  }

  // final l reduction (once): sum over the 4 quads holding each q-row
#pragma unroll
  for (int h = 0; h < 2; ++h) {
    lr[h] += __shfl_xor(lr[h], 16, 64);
    lr[h] += __shfl_xor(lr[h], 32, 64);
  }
  unsigned short* cp = ctx + slab;
#pragma unroll
  for (int h = 0; h < 2; ++h) {
    float lb[4];
#pragma unroll
    for (int r = 0; r < 4; ++r)
      lb[r] = 1.0f / __shfl(lr[h], quad * 4 + r, 64);
#pragma unroll
    for (int j = 0; j < 4; ++j)
#pragma unroll
      for (int r = 0; r < 4; ++r)
        cp[(size_t)(q0 + h * 16 + quad * 4 + r) * HDIM + j * 16 + l16] =
            f2bf(o[h][j][r] * lb[r]);
  }
}

// ---- residual + LayerNorm + exact GELU (erf), one block per row, float4 ----
__global__ __launch_bounds__(256) void ln_gelu(
    const float* __restrict__ x, const float* __restrict__ y,
    const float* __restrict__ gamma, const float* __restrict__ beta,
    float* __restrict__ out) {
  const int row = blockIdx.x;
  const int tid = threadIdx.x;
  const float4 xv = ((const float4*)(x + (size_t)row * DIM))[tid];
  const float4 yv = ((const float4*)(y + (size_t)row * DIM))[tid];
  float4 s;
  s.x = xv.x + yv.x; s.y = xv.y + yv.y; s.z = xv.z + yv.z; s.w = xv.w + yv.w;
  float sum = (s.x + s.y) + (s.z + s.w);
  float sq  = (s.x * s.x + s.y * s.y) + (s.z * s.z + s.w * s.w);
#pragma unroll
  for (int off = 1; off < 64; off <<= 1) {
    sum += __shfl_xor(sum, off, 64);
    sq  += __shfl_xor(sq, off, 64);
  }
  __shared__ float red[8];
  const int wave = tid >> 6, lane = tid & 63;
  if (lane == 0) { red[wave] = sum; red[wave + 4] = sq; }
  __syncthreads();
  sum = red[0] + red[1] + red[2] + red[3];
  sq  = red[4] + red[5] + red[6] + red[7];
  const float mu   = sum * (1.0f / DIM);
  const float var  = sq * (1.0f / DIM) - mu * mu;
  const float rstd = rsqrtf(var + 1e-5f);
  const float4 gv = ((const float4*)gamma)[tid];
  const float4 bv = ((const float4*)beta)[tid];
  float4 ov;
  {
    const float v = (s.x - mu) * rstd * gv.x + bv.x;
    ov.x = 0.5f * v * (1.0f + erff(v * 0.70710678118654752f));
  }
  {
    const float v = (s.y - mu) * rstd * gv.y + bv.y;
    ov.y = 0.5f * v * (1.0f + erff(v * 0.70710678118654752f));
  }
  {
    const float v = (s.z - mu) * rstd * gv.z + bv.z;
    ov.z = 0.5f * v * (1.0f + erff(v * 0.70710678118654752f));
  }
  {
    const float v = (s.w - mu) * rstd * gv.w + bv.w;
    ov.w = 0.5f * v * (1.0f + erff(v * 0.70710678118654752f));
  }
  ((float4*)(out + (size_t)row * DIM))[tid] = ov;
}

// ---------------------------------------------------------------------------
extern "C" void kernel_launch(void* const* d_in, const int* in_sizes, int n_in,
                              void* d_out, int out_size, void* d_ws, size_t ws_size,
                              hipStream_t stream) {
  (void)in_sizes; (void)n_in; (void)out_size; (void)ws_size;
  const float* x     = (const float*)d_in[0];
  const float* Wq    = (const float*)d_in[1];
  const float* bq    = (const float*)d_in[2];
  const float* Wk    = (const float*)d_in[3];
  const float* bk    = (const float*)d_in[4];
  const float* Wv    = (const float*)d_in[5];
  const float* bv    = (const float*)d_in[6];
  const float* Wo    = (const float*)d_in[7];
  const float* bo    = (const float*)d_in[8];
  const float* gamma = (const float*)d_in[9];
  const float* beta  = (const float*)d_in[10];
  float* out = (float*)d_out;

  char* ws = (char*)d_ws;
  const size_t MB = 1u << 20;
  unsigned short* xb    = (unsigned short*)(ws);             //  8 MB
  unsigned short* Wqkvt = (unsigned short*)(ws + 8 * MB);    //  6 MB
  unsigned short* Wot   = (unsigned short*)(ws + 14 * MB);   //  2 MB
  unsigned short* Qb    = (unsigned short*)(ws + 16 * MB);   //  8 MB
  unsigned short* Kb    = (unsigned short*)(ws + 24 * MB);   //  8 MB (swizzled in-place -> Ks)
  unsigned short* VbT   = (unsigned short*)(ws + 32 * MB);   //  8 MB (dead after swizzle_kv)
  unsigned short* Cx    = (unsigned short*)(ws + 32 * MB);   //  8 MB (reuses VbT slot)
  unsigned short* Vb    = (unsigned short*)(ws + 40 * MB);   //  8 MB (dead after transpose_v)
  unsigned short* Vs    = (unsigned short*)(ws + 40 * MB);   //  8 MB (reuses Vb slot)
  float*          Y     = (float*)(ws + 48 * MB);            // 16 MB

  cvt_bf16<<<(ROWS * DIM / 4 + 255) / 256, 256, 0, stream>>>(x, xb, ROWS * DIM / 4);
  transpose_w4<<<dim3(32, 32, 4), dim3(32, 8), 0, stream>>>(Wq, Wk, Wv, Wo, Wqkvt, Wot);

  gemm_qkv<<<dim3(24, 32), 256, 0, stream>>>(xb, Wqkvt, bq, bk, bv, Qb, Kb, Vb);
  transpose_v<<<dim3(SEQ / 64, 32), dim3(64, 4), 0, stream>>>(Vb, VbT);
  swizzle_kv<<<dim3(SEQ / 64, 32, 2), 256, 0, stream>>>(Kb, VbT, Vs);
  attn_fwd<<<dim3(32, 32), 128, 0, stream>>>(Qb, Kb, Vs, Cx);
  gemm_o<<<dim3(16, 32), 256, 0, stream>>>(Cx, Wot, bo, Y);
  ln_gelu<<<ROWS, 256, 0, stream>>>(x, Y, gamma, beta, out);
}

// Round 12
// 220.449 us; speedup vs baseline: 1.3487x; 1.0304x over previous
//
#include <hip/hip_runtime.h>
#include <hip/hip_bf16.h>
#include <cstdint>
#include <cstddef>

// ---------------------------------------------------------------------------
// MultiheadSelfAttention fused pipeline for MI355X (gfx950)
// Head bh = contiguous slab of the FLAT projection output (torch-faithful
// reshape without transpose): slab = (2048,64) row-major at bh*131072.
// Q pre-scaled by 0.125*log2(e) in gemm_qkv; MAX-FREE exp2 softmax.
// Round 12: SPLIT-K attention. Max-free softmax partials over disjoint key
// halves merge by pure addition: ctx = (O1+O2)/(l1+l2). 2048 blocks =
// 16 waves/CU (R11 was latency-bound at 8 waves/CU, no pipe >35%).
// XCD-aware decode (xcd=id&7 -> 4 dedicated heads, 2MB K/V set < 4MB L2).
// swizzle_kv reads V directly from Vb (slab-view tile is contiguous, same
// as K) -> transpose_v launch deleted.
// ---------------------------------------------------------------------------

#define SEQ   2048
#define DIM   1024
#define NHEAD 16
#define HDIM  64
#define ROWS  4096   // B*S

#define QSCALE 0.1803368801111204f   // 0.125 * log2(e)

typedef __attribute__((ext_vector_type(8))) __bf16 bf16x8;
typedef __attribute__((ext_vector_type(4))) float floatx4;
typedef __attribute__((ext_vector_type(8))) unsigned short ushortx8;

__device__ __forceinline__ unsigned short f2bf(float f) {
  unsigned int u = __float_as_uint(f);
  u += 0x7FFFu + ((u >> 16) & 1u);   // round-to-nearest-even
  return (unsigned short)(u >> 16);
}

__device__ __forceinline__ unsigned int pk2bf(float a, float b) {
  float2 f; f.x = a; f.y = b;                       // x -> low 16
  __hip_bfloat162 h = __float22bfloat162_rn(f);
  return *(unsigned int*)&h;
}

// async global->LDS, 16B/lane; LDS dest = wave-uniform base + lane*16 (m104)
__device__ __forceinline__ void glds16(const unsigned short* g,
                                       unsigned short* l) {
  __builtin_amdgcn_global_load_lds(
      (const __attribute__((address_space(1))) void*)g,
      (__attribute__((address_space(3))) void*)l, 16, 0, 0);
}

// ---- fp32 -> bf16 elementwise convert (vectorized float4 -> 4x bf16) -------
__global__ __launch_bounds__(256) void cvt_bf16(const float* __restrict__ in,
                                                unsigned short* __restrict__ out,
                                                int n4) {
  int i = blockIdx.x * 256 + threadIdx.x;
  if (i >= n4) return;
  float4 v = ((const float4*)in)[i];
  ushort4 o;
  o.x = f2bf(v.x); o.y = f2bf(v.y); o.z = f2bf(v.z); o.w = f2bf(v.w);
  ((ushort4*)out)[i] = o;
}

// ---- 4x (1024x1024 fp32 -> transposed bf16), one launch (z = matrix) -------
__global__ __launch_bounds__(256) void transpose_w4(
    const float* __restrict__ Wq, const float* __restrict__ Wk,
    const float* __restrict__ Wv, const float* __restrict__ Wo,
    unsigned short* __restrict__ Wqkvt, unsigned short* __restrict__ Wot) {
  __shared__ float t[32][33];
  const int z = blockIdx.z;
  const float* in = (z == 0) ? Wq : (z == 1) ? Wk : (z == 2) ? Wv : Wo;
  unsigned short* out = (z < 3) ? Wqkvt + (size_t)z * DIM * DIM : Wot;
  const int bx = blockIdx.x * 32, by = blockIdx.y * 32;
  const int tx = threadIdx.x, ty = threadIdx.y;
#pragma unroll
  for (int i = ty; i < 32; i += 8)
    t[i][tx] = in[(size_t)(by + i) * DIM + bx + tx];
  __syncthreads();
#pragma unroll
  for (int i = ty; i < 32; i += 8)
    out[(size_t)(bx + i) * DIM + by + tx] = f2bf(t[tx][i]);
}

// ---- swizzle K (in-place) and V (from projection layout) to frag-major -----
// Tile (64 keys x 64 ch) of BOTH K and V is the contiguous 8KB block at
// slab + tile*4096 (slab view). Frag f=step*4+g is 64 lanes x 16B contiguous:
//   K: frag[lane] = K[key = g*16+l16][step*32+quad*8 ..+7]     (row copy)
//   V: frag[lane] = V[key = step*32+quad*8+e][d = g*16+l16]    (transpose)
__global__ __launch_bounds__(256) void swizzle_kv(
    unsigned short* __restrict__ Kb,         // in/out (in-place)
    const unsigned short* __restrict__ Vb,   // in (projection layout)
    unsigned short* __restrict__ Vs) {       // out fragment-major
  __shared__ unsigned short t[64 * 72];
  const int tile = blockIdx.x;               // 0..31 (key tile)
  const int bh   = blockIdx.y;               // 0..31
  const int isV  = blockIdx.z;
  const int tid  = threadIdx.x;
  const size_t base = (size_t)bh * (SEQ * HDIM) + (size_t)tile * 4096;
  const unsigned short* src = (isV ? Vb : Kb) + base;
#pragma unroll
  for (int p = 0; p < 2; ++p) {
    const int c = p * 256 + tid;
    *(ushortx8*)&t[(c >> 3) * 72 + (c & 7) * 8] = *(const ushortx8*)&src[c * 8];
  }
  __syncthreads();
  unsigned short* dst = (isV ? Vs : Kb) + base;
  const int lane = tid & 63, wave = tid >> 6;
  const int l16 = lane & 15, quad = lane >> 4;
  if (!isV) {
#pragma unroll
    for (int p = 0; p < 2; ++p) {
      const int f = wave * 2 + p;
      const int step = f >> 2, g = f & 3;
      *(ushortx8*)&dst[f * 512 + lane * 8] =
          *(const ushortx8*)&t[(g * 16 + l16) * 72 + step * 32 + quad * 8];
    }
  } else {
#pragma unroll
    for (int p = 0; p < 2; ++p) {
      const int f = wave * 2 + p;
      const int step = f >> 2, g = f & 3;
      ushortx8 v;
#pragma unroll
      for (int e = 0; e < 8; ++e)
        v[e] = t[(step * 32 + quad * 8 + e) * 72 + g * 16 + l16];
      *(ushortx8*)&dst[f * 512 + lane * 8] = v;
    }
  }
}

// ---------------------------------------------------------------------------
// Fused QKV GEMM, global_load_lds staging (m97 pattern). Unpadded LDS tiles.
// Q written PRE-SCALED by QSCALE (max-free exp2 softmax).
// ---------------------------------------------------------------------------
__global__ __launch_bounds__(256, 3) void gemm_qkv(
    const unsigned short* __restrict__ A,    // 4096 x 1024 bf16
    const unsigned short* __restrict__ Wt,   // 3072 x 1024 bf16
    const float* __restrict__ bq, const float* __restrict__ bk,
    const float* __restrict__ bv,
    unsigned short* __restrict__ Qb, unsigned short* __restrict__ Kb,
    unsigned short* __restrict__ Vb) {
  constexpr int K = DIM;
  __shared__ unsigned short As[128 * 64];    // unpadded (glds layout)
  __shared__ unsigned short Bs[128 * 64];
  const int tid  = threadIdx.x;
  const int lane = tid & 63, wave = tid >> 6;
  const int l16  = lane & 15, quad = lane >> 4;
  const int wm   = (wave & 1) * 64, wn = (wave >> 1) * 64;
  const int tm   = blockIdx.y * 128, tn = blockIdx.x * 128;
  const int grow = lane >> 3, gcol = (lane & 7) * 8;   // lane's 16B chunk

  floatx4 acc[4][4] = {};

  for (int k0 = 0; k0 < K; k0 += 64) {
    __syncthreads();
#pragma unroll
    for (int p = 0; p < 4; ++p) {
      const int q = wave * 4 + p;            // inst 0..15, rows 8q..8q+7
      const int row = q * 8 + grow;
      glds16(&A [(size_t)(tm + row) * K + k0 + gcol], &As[q * 512]);
      glds16(&Wt[(size_t)(tn + row) * K + k0 + gcol], &Bs[q * 512]);
    }
    __syncthreads();
#pragma unroll
    for (int step = 0; step < 2; ++step) {
      const int kk = step * 32 + quad * 8;
      bf16x8 af[4], bfr[4];
#pragma unroll
      for (int i = 0; i < 4; ++i)
        af[i] = *(const bf16x8*)&As[(wm + i * 16 + l16) * 64 + kk];
#pragma unroll
      for (int j = 0; j < 4; ++j)
        bfr[j] = *(const bf16x8*)&Bs[(wn + j * 16 + l16) * 64 + kk];
#pragma unroll
      for (int i = 0; i < 4; ++i)
#pragma unroll
        for (int j = 0; j < 4; ++j)
          acc[i][j] = __builtin_amdgcn_mfma_f32_16x16x32_bf16(af[i], bfr[j],
                                                              acc[i][j], 0, 0, 0);
    }
  }

#pragma unroll
  for (int j = 0; j < 4; ++j) {
    const int ng  = tn + wn + j * 16 + l16;   // output channel 0..3071
    const int seg = ng >> 10;                 // 0=Q 1=K 2=V
    const int col = ng & 1023;
    const float* bp    = (seg == 0) ? bq : (seg == 1) ? bk : bv;
    unsigned short* op = (seg == 0) ? Qb : (seg == 1) ? Kb : Vb;
    const float bias = bp[col];
    const float scl  = (seg == 0) ? QSCALE : 1.0f;
#pragma unroll
    for (int i = 0; i < 4; ++i) {
      const int m0 = tm + wm + i * 16 + quad * 4;
#pragma unroll
      for (int r = 0; r < 4; ++r)
        op[(size_t)(m0 + r) * DIM + col] = f2bf((acc[i][j][r] + bias) * scl);
    }
  }
}

// ---- Output projection GEMM: Y = ctx @ Wo + bo. 128x64 tiles (512 blocks),
// global_load_lds staging. ----------------------------------------------------
__global__ __launch_bounds__(256) void gemm_o(
    const unsigned short* __restrict__ A,    // 4096 x 1024 bf16 (ctx)
    const unsigned short* __restrict__ Wt,   // 1024 x 1024 bf16 (Wo^T)
    const float* __restrict__ bo,
    float* __restrict__ Y) {
  constexpr int K = DIM;
  __shared__ unsigned short As[128 * 64];    // unpadded (glds layout)
  __shared__ unsigned short Bs[64 * 64];
  const int tid  = threadIdx.x;
  const int lane = tid & 63, wave = tid >> 6;
  const int l16  = lane & 15, quad = lane >> 4;
  const int wm   = wave * 32;                 // wave owns 32 rows, all 64 cols
  const int tm   = blockIdx.y * 128, tn = blockIdx.x * 64;
  const int grow = lane >> 3, gcol = (lane & 7) * 8;

  floatx4 acc[2][4] = {};

  for (int k0 = 0; k0 < K; k0 += 64) {
    __syncthreads();
#pragma unroll
    for (int p = 0; p < 4; ++p) {
      const int q = wave * 4 + p;            // 0..15
      const int row = q * 8 + grow;
      glds16(&A[(size_t)(tm + row) * K + k0 + gcol], &As[q * 512]);
    }
#pragma unroll
    for (int p = 0; p < 2; ++p) {
      const int q = wave * 2 + p;            // 0..7
      const int row = q * 8 + grow;
      glds16(&Wt[(size_t)(tn + row) * K + k0 + gcol], &Bs[q * 512]);
    }
    __syncthreads();
#pragma unroll
    for (int step = 0; step < 2; ++step) {
      const int kk = step * 32 + quad * 8;
      bf16x8 af[2], bfr[4];
#pragma unroll
      for (int i = 0; i < 2; ++i)
        af[i] = *(const bf16x8*)&As[(wm + i * 16 + l16) * 64 + kk];
#pragma unroll
      for (int j = 0; j < 4; ++j)
        bfr[j] = *(const bf16x8*)&Bs[(j * 16 + l16) * 64 + kk];
#pragma unroll
      for (int i = 0; i < 2; ++i)
#pragma unroll
        for (int j = 0; j < 4; ++j)
          acc[i][j] = __builtin_amdgcn_mfma_f32_16x16x32_bf16(af[i], bfr[j],
                                                              acc[i][j], 0, 0, 0);
    }
  }

#pragma unroll
  for (int j = 0; j < 4; ++j) {
    const int n = tn + j * 16 + l16;
    const float bias = bo[n];
#pragma unroll
    for (int i = 0; i < 2; ++i) {
      const int m0 = tm + wm + i * 16 + quad * 4;
#pragma unroll
      for (int r = 0; r < 4; ++r)
        Y[(size_t)(m0 + r) * DIM + n] = acc[i][j][r] + bias;
    }
  }
}

// ---------------------------------------------------------------------------
// Flash attention, SPLIT-K, barrier-free. 2048 blocks x 128 thr = 16 waves/CU.
// Decode (XCD-aware, assumes xcd = id&7 round-robin; wrong guess = harmless
// permutation): head = (id&7)*4 + (w&3), qtile = (w>>2)&31, half = w>>7,
// w = id>>3. Each block: 32 qrows/wave x 2 waves over 16 key tiles (one
// half). Writes UNNORMALIZED O (bf16) + l (fp32) partials; max-free softmax
// makes the merge pure addition.
// ---------------------------------------------------------------------------
__global__ __launch_bounds__(128) void attn_fwd(
    const unsigned short* __restrict__ Qb,
    const unsigned short* __restrict__ Ks,   // fragment-major K
    const unsigned short* __restrict__ Vs,   // fragment-major V^T
    unsigned short* __restrict__ Op0, unsigned short* __restrict__ Op1,
    float* __restrict__ l0, float* __restrict__ l1) {
  __shared__ unsigned short Pl[2][32 * 72];   // per-wave P [qrow 0..31][key]

  const int tid  = threadIdx.x;               // 0..127
  const int lane = tid & 63, wave = tid >> 6; // wave 0..1
  const int l16  = lane & 15, quad = lane >> 4;
  const int id   = blockIdx.x;
  const int w    = id >> 3;
  const int head = (id & 7) * 4 + (w & 3);    // 4 heads per XCD
  const int qt   = (w >> 2) & 31;
  const int half = w >> 7;                    // 0/1: key range half
  const size_t slab = (size_t)head * SEQ * HDIM;
  const unsigned short* Q  = Qb + slab;
  const unsigned short* Kf = Ks + slab;
  const unsigned short* Vf = Vs + slab;
  const int q0 = qt * 64 + wave * 32;

  // Q fragments (pre-scaled by QSCALE): B-operand, halves h=0,1
  bf16x8 qf[2][2];
#pragma unroll
  for (int h = 0; h < 2; ++h) {
    qf[h][0] = *(const bf16x8*)&Q[(size_t)(q0 + h * 16 + l16) * HDIM + quad * 8];
    qf[h][1] = *(const bf16x8*)&Q[(size_t)(q0 + h * 16 + l16) * HDIM + 32 + quad * 8];
  }

  floatx4 o[2][4] = {};
  float lr[2] = {0.f, 0.f};

  for (int t = 0; t < 16; ++t) {
    const int tile = half * 16 + t;
    const unsigned short* kb = Kf + (size_t)tile * 4096;
    const unsigned short* vb = Vf + (size_t)tile * 4096;
    bf16x8 kf[2][4], vf[2][4];
#pragma unroll
    for (int step = 0; step < 2; ++step)
#pragma unroll
      for (int g = 0; g < 4; ++g) {
        kf[step][g] = *(const bf16x8*)&kb[(step * 4 + g) * 512 + lane * 8];
        vf[step][g] = *(const bf16x8*)&vb[(step * 4 + g) * 512 + lane * 8];
      }

    // S^T = K Q^T, both q-halves share each K fragment
    floatx4 s[2][4] = {};
#pragma unroll
    for (int step = 0; step < 2; ++step)
#pragma unroll
      for (int mt = 0; mt < 4; ++mt) {
        s[0][mt] = __builtin_amdgcn_mfma_f32_16x16x32_bf16(kf[step][mt], qf[0][step], s[0][mt], 0, 0, 0);
        s[1][mt] = __builtin_amdgcn_mfma_f32_16x16x32_bf16(kf[step][mt], qf[1][step], s[1][mt], 0, 0, 0);
      }

    // max-free softmax: p = exp2(s'), accumulate l per-lane, pack P -> LDS
#pragma unroll
    for (int h = 0; h < 2; ++h) {
#pragma unroll
      for (int mt = 0; mt < 4; ++mt) {
        float p0 = __builtin_amdgcn_exp2f(s[h][mt][0]);
        float p1 = __builtin_amdgcn_exp2f(s[h][mt][1]);
        float p2 = __builtin_amdgcn_exp2f(s[h][mt][2]);
        float p3 = __builtin_amdgcn_exp2f(s[h][mt][3]);
        lr[h] += (p0 + p1) + (p2 + p3);
        uint2 pv;
        pv.x = pk2bf(p0, p1);
        pv.y = pk2bf(p2, p3);
        *(uint2*)&Pl[wave][(h * 16 + l16) * 72 + mt * 16 + quad * 4] = pv;
      }
    }
    // per-wave LDS RAW: drain ds queue; clobber stops compiler reordering
    __asm__ __volatile__("s_waitcnt lgkmcnt(0)" ::: "memory");

    // O += P V, both halves share each V fragment
#pragma unroll
    for (int step = 0; step < 2; ++step) {
      const int kk = step * 32 + quad * 8;
      bf16x8 pf0 = *(const bf16x8*)&Pl[wave][(l16) * 72 + kk];
      bf16x8 pf1 = *(const bf16x8*)&Pl[wave][(16 + l16) * 72 + kk];
#pragma unroll
      for (int j = 0; j < 4; ++j) {
        o[0][j] = __builtin_amdgcn_mfma_f32_16x16x32_bf16(pf0, vf[step][j], o[0][j], 0, 0, 0);
        o[1][j] = __builtin_amdgcn_mfma_f32_16x16x32_bf16(pf1, vf[step][j], o[1][j], 0, 0, 0);
      }
    }
  }

  // l reduction, then write UNNORMALIZED partials for this half
#pragma unroll
  for (int h = 0; h < 2; ++h) {
    lr[h] += __shfl_xor(lr[h], 16, 64);
    lr[h] += __shfl_xor(lr[h], 32, 64);
  }
  unsigned short* Op = half ? Op1 : Op0;
  float*          lp = half ? l1 : l0;
#pragma unroll
  for (int h = 0; h < 2; ++h) {
    if (quad == 0)
      lp[head * SEQ + q0 + h * 16 + l16] = lr[h];
#pragma unroll
    for (int j = 0; j < 4; ++j)
#pragma unroll
      for (int r = 0; r < 4; ++r)
        Op[slab + (size_t)(q0 + h * 16 + quad * 4 + r) * HDIM + j * 16 + l16] =
            f2bf(o[h][j][r]);
  }
}

// ---- merge split-K partials: ctx = (O0+O1)/(l0+l1) -------------------------
// element idx e = head*131072 + q*64 + d  ->  l index = e>>6.
__global__ __launch_bounds__(256) void attn_merge(
    const unsigned short* __restrict__ Op0,
    const unsigned short* __restrict__ Op1,
    const float* __restrict__ l0, const float* __restrict__ l1,
    unsigned short* __restrict__ Cx) {
  const int i = blockIdx.x * 256 + threadIdx.x;   // chunk of 8 elements
  const float inv = 1.0f / (l0[i >> 3] + l1[i >> 3]);
  ushortx8 a = *(const ushortx8*)&Op0[(size_t)i * 8];
  ushortx8 b = *(const ushortx8*)&Op1[(size_t)i * 8];
  ushortx8 o;
#pragma unroll
  for (int e = 0; e < 8; ++e) {
    const float fa = __uint_as_float((unsigned int)a[e] << 16);
    const float fb = __uint_as_float((unsigned int)b[e] << 16);
    o[e] = f2bf((fa + fb) * inv);
  }
  *(ushortx8*)&Cx[(size_t)i * 8] = o;
}

// ---- residual + LayerNorm + exact GELU (erf), one block per row, float4 ----
__global__ __launch_bounds__(256) void ln_gelu(
    const float* __restrict__ x, const float* __restrict__ y,
    const float* __restrict__ gamma, const float* __restrict__ beta,
    float* __restrict__ out) {
  const int row = blockIdx.x;
  const int tid = threadIdx.x;
  const float4 xv = ((const float4*)(x + (size_t)row * DIM))[tid];
  const float4 yv = ((const float4*)(y + (size_t)row * DIM))[tid];
  float4 s;
  s.x = xv.x + yv.x; s.y = xv.y + yv.y; s.z = xv.z + yv.z; s.w = xv.w + yv.w;
  float sum = (s.x + s.y) + (s.z + s.w);
  float sq  = (s.x * s.x + s.y * s.y) + (s.z * s.z + s.w * s.w);
#pragma unroll
  for (int off = 1; off < 64; off <<= 1) {
    sum += __shfl_xor(sum, off, 64);
    sq  += __shfl_xor(sq, off, 64);
  }
  __shared__ float red[8];
  const int wave = tid >> 6, lane = tid & 63;
  if (lane == 0) { red[wave] = sum; red[wave + 4] = sq; }
  __syncthreads();
  sum = red[0] + red[1] + red[2] + red[3];
  sq  = red[4] + red[5] + red[6] + red[7];
  const float mu   = sum * (1.0f / DIM);
  const float var  = sq * (1.0f / DIM) - mu * mu;
  const float rstd = rsqrtf(var + 1e-5f);
  const float4 gv = ((const float4*)gamma)[tid];
  const float4 bv = ((const float4*)beta)[tid];
  float4 ov;
  {
    const float v = (s.x - mu) * rstd * gv.x + bv.x;
    ov.x = 0.5f * v * (1.0f + erff(v * 0.70710678118654752f));
  }
  {
    const float v = (s.y - mu) * rstd * gv.y + bv.y;
    ov.y = 0.5f * v * (1.0f + erff(v * 0.70710678118654752f));
  }
  {
    const float v = (s.z - mu) * rstd * gv.z + bv.z;
    ov.z = 0.5f * v * (1.0f + erff(v * 0.70710678118654752f));
  }
  {
    const float v = (s.w - mu) * rstd * gv.w + bv.w;
    ov.w = 0.5f * v * (1.0f + erff(v * 0.70710678118654752f));
  }
  ((float4*)(out + (size_t)row * DIM))[tid] = ov;
}

// ---------------------------------------------------------------------------
extern "C" void kernel_launch(void* const* d_in, const int* in_sizes, int n_in,
                              void* d_out, int out_size, void* d_ws, size_t ws_size,
                              hipStream_t stream) {
  (void)in_sizes; (void)n_in; (void)out_size; (void)ws_size;
  const float* x     = (const float*)d_in[0];
  const float* Wq    = (const float*)d_in[1];
  const float* bq    = (const float*)d_in[2];
  const float* Wk    = (const float*)d_in[3];
  const float* bk    = (const float*)d_in[4];
  const float* Wv    = (const float*)d_in[5];
  const float* bv    = (const float*)d_in[6];
  const float* Wo    = (const float*)d_in[7];
  const float* bo    = (const float*)d_in[8];
  const float* gamma = (const float*)d_in[9];
  const float* beta  = (const float*)d_in[10];
  float* out = (float*)d_out;

  // Workspace layout with lifetime-based aliasing (64 MB total):
  //  0- 8: xb (prep/gemm_qkv)          | Op0  (attn/merge)
  //  8-14: Wqkvt (prep/gemm_qkv)       | lp0 @8.0M, lp1 @8.25M (attn/merge)
  // 14-16: Wot (prep, read by gemm_o)
  // 16-24: Qb
  // 24-32: Kb -> Ks (swizzled in-place)
  // 32-40: Vs (frag-major V)
  // 40-48: Vb (gemm_qkv/swizzle)       | Cx (merge/gemm_o)
  // 48-64: Y (gemm_o/ln_gelu)          | Op1 @48-56 (attn/merge)
  char* ws = (char*)d_ws;
  const size_t MB = 1u << 20;
  unsigned short* xb    = (unsigned short*)(ws);
  unsigned short* Op0   = (unsigned short*)(ws);
  unsigned short* Wqkvt = (unsigned short*)(ws + 8 * MB);
  float*          lp0   = (float*)(ws + 8 * MB);
  float*          lp1   = (float*)(ws + 8 * MB + 256 * 1024);
  unsigned short* Wot   = (unsigned short*)(ws + 14 * MB);
  unsigned short* Qb    = (unsigned short*)(ws + 16 * MB);
  unsigned short* Kb    = (unsigned short*)(ws + 24 * MB);
  unsigned short* Vs    = (unsigned short*)(ws + 32 * MB);
  unsigned short* Vb    = (unsigned short*)(ws + 40 * MB);
  unsigned short* Cx    = (unsigned short*)(ws + 40 * MB);
  float*          Y     = (float*)(ws + 48 * MB);
  unsigned short* Op1   = (unsigned short*)(ws + 48 * MB);

  cvt_bf16<<<(ROWS * DIM / 4 + 255) / 256, 256, 0, stream>>>(x, xb, ROWS * DIM / 4);
  transpose_w4<<<dim3(32, 32, 4), dim3(32, 8), 0, stream>>>(Wq, Wk, Wv, Wo, Wqkvt, Wot);

  gemm_qkv<<<dim3(24, 32), 256, 0, stream>>>(xb, Wqkvt, bq, bk, bv, Qb, Kb, Vb);
  swizzle_kv<<<dim3(SEQ / 64, 32, 2), 256, 0, stream>>>(Kb, Vb, Vs);
  attn_fwd<<<2048, 128, 0, stream>>>(Qb, Kb, Vs, Op0, Op1, lp0, lp1);
  attn_merge<<<(ROWS * DIM) / (8 * 256), 256, 0, stream>>>(Op0, Op1, lp0, lp1, Cx);
  gemm_o<<<dim3(16, 32), 256, 0, stream>>>(Cx, Wot, bo, Y);
  ln_gelu<<<ROWS, 256, 0, stream>>>(x, Y, gamma, beta, out);
}

// Round 13
// 218.612 us; speedup vs baseline: 1.3601x; 1.0084x over previous
//
#include <hip/hip_runtime.h>
#include <hip/hip_bf16.h>
#include <cstdint>
#include <cstddef>

// ---------------------------------------------------------------------------
// MultiheadSelfAttention fused pipeline for MI355X (gfx950)
// Head bh = contiguous slab of the FLAT projection output (torch-faithful
// reshape without transpose): slab = (2048,64) row-major at bh*131072.
// Q pre-scaled by 0.125*log2(e) in gemm_qkv; MAX-FREE exp2 softmax.
// Round 13: in-block SPLIT-K x4 attention — 4 waves each own a key-quarter
// of the SAME 32 q-rows; partials merge in-LDS (pure addition, max-free)
// and ctx is written directly. attn_merge kernel + Op/l global round-trip
// deleted. 2048 blocks x 256 thr = 24 waves/CU (VGPR-capped; R12 was 16).
// XCD-aware decode keeps 4 heads per XCD (R12: FETCH 86->12 MB).
// prep: x-convert fused into the weight-transpose launch (z=4).
// ---------------------------------------------------------------------------

#define SEQ   2048
#define DIM   1024
#define NHEAD 16
#define HDIM  64
#define ROWS  4096   // B*S

#define QSCALE 0.1803368801111204f   // 0.125 * log2(e)

typedef __attribute__((ext_vector_type(8))) __bf16 bf16x8;
typedef __attribute__((ext_vector_type(4))) float floatx4;
typedef __attribute__((ext_vector_type(8))) unsigned short ushortx8;

__device__ __forceinline__ unsigned short f2bf(float f) {
  unsigned int u = __float_as_uint(f);
  u += 0x7FFFu + ((u >> 16) & 1u);   // round-to-nearest-even
  return (unsigned short)(u >> 16);
}

__device__ __forceinline__ unsigned int pk2bf(float a, float b) {
  float2 f; f.x = a; f.y = b;                       // x -> low 16
  __hip_bfloat162 h = __float22bfloat162_rn(f);
  return *(unsigned int*)&h;
}

// async global->LDS, 16B/lane; LDS dest = wave-uniform base + lane*16 (m104)
__device__ __forceinline__ void glds16(const unsigned short* g,
                                       unsigned short* l) {
  __builtin_amdgcn_global_load_lds(
      (const __attribute__((address_space(1))) void*)g,
      (__attribute__((address_space(3))) void*)l, 16, 0, 0);
}

// ---- prep: z=0..3 -> 1024x1024 fp32 W -> transposed bf16; z=4 -> cvt x -----
__global__ __launch_bounds__(256) void prep_all(
    const float* __restrict__ x,
    const float* __restrict__ Wq, const float* __restrict__ Wk,
    const float* __restrict__ Wv, const float* __restrict__ Wo,
    unsigned short* __restrict__ xb,
    unsigned short* __restrict__ Wqkvt, unsigned short* __restrict__ Wot) {
  __shared__ float t[32][33];
  const int z = blockIdx.z;
  const int tx = threadIdx.x, ty = threadIdx.y;
  if (z == 4) {   // x fp32 -> bf16, 1024 blocks x 1024 float4-chunks
    const int bid = blockIdx.y * 32 + blockIdx.x;
    const int tid = ty * 32 + tx;
#pragma unroll
    for (int p = 0; p < 4; ++p) {
      const int i = bid * 1024 + p * 256 + tid;
      float4 v = ((const float4*)x)[i];
      ushort4 o;
      o.x = f2bf(v.x); o.y = f2bf(v.y); o.z = f2bf(v.z); o.w = f2bf(v.w);
      ((ushort4*)xb)[i] = o;
    }
    return;
  }
  const float* in = (z == 0) ? Wq : (z == 1) ? Wk : (z == 2) ? Wv : Wo;
  unsigned short* out = (z < 3) ? Wqkvt + (size_t)z * DIM * DIM : Wot;
  const int bx = blockIdx.x * 32, by = blockIdx.y * 32;
#pragma unroll
  for (int i = ty; i < 32; i += 8)
    t[i][tx] = in[(size_t)(by + i) * DIM + bx + tx];
  __syncthreads();
#pragma unroll
  for (int i = ty; i < 32; i += 8)
    out[(size_t)(bx + i) * DIM + by + tx] = f2bf(t[tx][i]);
}

// ---- swizzle K (in-place) and V (from projection layout) to frag-major -----
// Tile (64 keys x 64 ch) of BOTH K and V is the contiguous 8KB block at
// slab + tile*4096 (slab view). Frag f=step*4+g is 64 lanes x 16B contiguous:
//   K: frag[lane] = K[key = g*16+l16][step*32+quad*8 ..+7]     (row copy)
//   V: frag[lane] = V[key = step*32+quad*8+e][d = g*16+l16]    (transpose)
__global__ __launch_bounds__(256) void swizzle_kv(
    unsigned short* __restrict__ Kb,         // in/out (in-place)
    const unsigned short* __restrict__ Vb,   // in (projection layout)
    unsigned short* __restrict__ Vs) {       // out fragment-major
  __shared__ unsigned short t[64 * 72];
  const int tile = blockIdx.x;               // 0..31 (key tile)
  const int bh   = blockIdx.y;               // 0..31
  const int isV  = blockIdx.z;
  const int tid  = threadIdx.x;
  const size_t base = (size_t)bh * (SEQ * HDIM) + (size_t)tile * 4096;
  const unsigned short* src = (isV ? Vb : Kb) + base;
#pragma unroll
  for (int p = 0; p < 2; ++p) {
    const int c = p * 256 + tid;
    *(ushortx8*)&t[(c >> 3) * 72 + (c & 7) * 8] = *(const ushortx8*)&src[c * 8];
  }
  __syncthreads();
  unsigned short* dst = (isV ? Vs : Kb) + base;
  const int lane = tid & 63, wave = tid >> 6;
  const int l16 = lane & 15, quad = lane >> 4;
  if (!isV) {
#pragma unroll
    for (int p = 0; p < 2; ++p) {
      const int f = wave * 2 + p;
      const int step = f >> 2, g = f & 3;
      *(ushortx8*)&dst[f * 512 + lane * 8] =
          *(const ushortx8*)&t[(g * 16 + l16) * 72 + step * 32 + quad * 8];
    }
  } else {
#pragma unroll
    for (int p = 0; p < 2; ++p) {
      const int f = wave * 2 + p;
      const int step = f >> 2, g = f & 3;
      ushortx8 v;
#pragma unroll
      for (int e = 0; e < 8; ++e)
        v[e] = t[(step * 32 + quad * 8 + e) * 72 + g * 16 + l16];
      *(ushortx8*)&dst[f * 512 + lane * 8] = v;
    }
  }
}

// ---------------------------------------------------------------------------
// Fused QKV GEMM, global_load_lds staging (m97 pattern). Unpadded LDS tiles.
// Q written PRE-SCALED by QSCALE (max-free exp2 softmax).
// ---------------------------------------------------------------------------
__global__ __launch_bounds__(256, 3) void gemm_qkv(
    const unsigned short* __restrict__ A,    // 4096 x 1024 bf16
    const unsigned short* __restrict__ Wt,   // 3072 x 1024 bf16
    const float* __restrict__ bq, const float* __restrict__ bk,
    const float* __restrict__ bv,
    unsigned short* __restrict__ Qb, unsigned short* __restrict__ Kb,
    unsigned short* __restrict__ Vb) {
  constexpr int K = DIM;
  __shared__ unsigned short As[128 * 64];    // unpadded (glds layout)
  __shared__ unsigned short Bs[128 * 64];
  const int tid  = threadIdx.x;
  const int lane = tid & 63, wave = tid >> 6;
  const int l16  = lane & 15, quad = lane >> 4;
  const int wm   = (wave & 1) * 64, wn = (wave >> 1) * 64;
  const int tm   = blockIdx.y * 128, tn = blockIdx.x * 128;
  const int grow = lane >> 3, gcol = (lane & 7) * 8;   // lane's 16B chunk

  floatx4 acc[4][4] = {};

  for (int k0 = 0; k0 < K; k0 += 64) {
    __syncthreads();
#pragma unroll
    for (int p = 0; p < 4; ++p) {
      const int q = wave * 4 + p;            // inst 0..15, rows 8q..8q+7
      const int row = q * 8 + grow;
      glds16(&A [(size_t)(tm + row) * K + k0 + gcol], &As[q * 512]);
      glds16(&Wt[(size_t)(tn + row) * K + k0 + gcol], &Bs[q * 512]);
    }
    __syncthreads();
#pragma unroll
    for (int step = 0; step < 2; ++step) {
      const int kk = step * 32 + quad * 8;
      bf16x8 af[4], bfr[4];
#pragma unroll
      for (int i = 0; i < 4; ++i)
        af[i] = *(const bf16x8*)&As[(wm + i * 16 + l16) * 64 + kk];
#pragma unroll
      for (int j = 0; j < 4; ++j)
        bfr[j] = *(const bf16x8*)&Bs[(wn + j * 16 + l16) * 64 + kk];
#pragma unroll
      for (int i = 0; i < 4; ++i)
#pragma unroll
        for (int j = 0; j < 4; ++j)
          acc[i][j] = __builtin_amdgcn_mfma_f32_16x16x32_bf16(af[i], bfr[j],
                                                              acc[i][j], 0, 0, 0);
    }
  }

#pragma unroll
  for (int j = 0; j < 4; ++j) {
    const int ng  = tn + wn + j * 16 + l16;   // output channel 0..3071
    const int seg = ng >> 10;                 // 0=Q 1=K 2=V
    const int col = ng & 1023;
    const float* bp    = (seg == 0) ? bq : (seg == 1) ? bk : bv;
    unsigned short* op = (seg == 0) ? Qb : (seg == 1) ? Kb : Vb;
    const float bias = bp[col];
    const float scl  = (seg == 0) ? QSCALE : 1.0f;
#pragma unroll
    for (int i = 0; i < 4; ++i) {
      const int m0 = tm + wm + i * 16 + quad * 4;
#pragma unroll
      for (int r = 0; r < 4; ++r)
        op[(size_t)(m0 + r) * DIM + col] = f2bf((acc[i][j][r] + bias) * scl);
    }
  }
}

// ---- Output projection GEMM: Y = ctx @ Wo + bo. 128x64 tiles (512 blocks),
// global_load_lds staging. ----------------------------------------------------
__global__ __launch_bounds__(256) void gemm_o(
    const unsigned short* __restrict__ A,    // 4096 x 1024 bf16 (ctx)
    const unsigned short* __restrict__ Wt,   // 1024 x 1024 bf16 (Wo^T)
    const float* __restrict__ bo,
    float* __restrict__ Y) {
  constexpr int K = DIM;
  __shared__ unsigned short As[128 * 64];    // unpadded (glds layout)
  __shared__ unsigned short Bs[64 * 64];
  const int tid  = threadIdx.x;
  const int lane = tid & 63, wave = tid >> 6;
  const int l16  = lane & 15, quad = lane >> 4;
  const int wm   = wave * 32;                 // wave owns 32 rows, all 64 cols
  const int tm   = blockIdx.y * 128, tn = blockIdx.x * 64;
  const int grow = lane >> 3, gcol = (lane & 7) * 8;

  floatx4 acc[2][4] = {};

  for (int k0 = 0; k0 < K; k0 += 64) {
    __syncthreads();
#pragma unroll
    for (int p = 0; p < 4; ++p) {
      const int q = wave * 4 + p;            // 0..15
      const int row = q * 8 + grow;
      glds16(&A[(size_t)(tm + row) * K + k0 + gcol], &As[q * 512]);
    }
#pragma unroll
    for (int p = 0; p < 2; ++p) {
      const int q = wave * 2 + p;            // 0..7
      const int row = q * 8 + grow;
      glds16(&Wt[(size_t)(tn + row) * K + k0 + gcol], &Bs[q * 512]);
    }
    __syncthreads();
#pragma unroll
    for (int step = 0; step < 2; ++step) {
      const int kk = step * 32 + quad * 8;
      bf16x8 af[2], bfr[4];
#pragma unroll
      for (int i = 0; i < 2; ++i)
        af[i] = *(const bf16x8*)&As[(wm + i * 16 + l16) * 64 + kk];
#pragma unroll
      for (int j = 0; j < 4; ++j)
        bfr[j] = *(const bf16x8*)&Bs[(j * 16 + l16) * 64 + kk];
#pragma unroll
      for (int i = 0; i < 2; ++i)
#pragma unroll
        for (int j = 0; j < 4; ++j)
          acc[i][j] = __builtin_amdgcn_mfma_f32_16x16x32_bf16(af[i], bfr[j],
                                                              acc[i][j], 0, 0, 0);
    }
  }

#pragma unroll
  for (int j = 0; j < 4; ++j) {
    const int n = tn + j * 16 + l16;
    const float bias = bo[n];
#pragma unroll
    for (int i = 0; i < 2; ++i) {
      const int m0 = tm + wm + i * 16 + quad * 4;
#pragma unroll
      for (int r = 0; r < 4; ++r)
        Y[(size_t)(m0 + r) * DIM + n] = acc[i][j][r] + bias;
    }
  }
}

// ---------------------------------------------------------------------------
// Flash attention, in-block SPLIT-K x4, barrier-free main loop. 2048 blocks
// x 256 thr = 24 waves/CU (VGPR-capped). Wave w handles key-quarter w
// (8 tiles) for the block's 32 q-rows. Max-free softmax => partials merge by
// addition: waves 1..3 dump bf16 O + fp32 l into their Pl slot, one barrier,
// wave 0 sums in fp32, normalizes, writes ctx.
// Decode (XCD-aware, xcd=id&7): head = (id&7)*4 + (w&3), qt = w>>2, w=id>>3.
// ---------------------------------------------------------------------------
__global__ __launch_bounds__(256) void attn_fwd(
    const unsigned short* __restrict__ Qb,
    const unsigned short* __restrict__ Ks,   // fragment-major K
    const unsigned short* __restrict__ Vs,   // fragment-major V^T
    unsigned short* __restrict__ ctx) {
  // per-wave slot: P staging (32x72 shorts) during loop; afterwards partial
  // O bf16 [row*64+col] (4096B) + l fp32 at short-offset 2048 (128B).
  __shared__ unsigned short Pl[4][32 * 72];

  const int tid  = threadIdx.x;               // 0..255
  const int lane = tid & 63, wave = tid >> 6; // wave 0..3 = key quarter
  const int l16  = lane & 15, quad = lane >> 4;
  const int id   = blockIdx.x;
  const int w    = id >> 3;
  const int head = (id & 7) * 4 + (w & 3);    // 4 heads per XCD
  const int qt   = w >> 2;                    // 0..63
  const size_t slab = (size_t)head * SEQ * HDIM;
  const unsigned short* Q  = Qb + slab;
  const unsigned short* Kf = Ks + slab;
  const unsigned short* Vf = Vs + slab;
  const int q0 = qt * 32;

  // Q fragments (pre-scaled by QSCALE): B-operand, halves h=0,1
  bf16x8 qf[2][2];
#pragma unroll
  for (int h = 0; h < 2; ++h) {
    qf[h][0] = *(const bf16x8*)&Q[(size_t)(q0 + h * 16 + l16) * HDIM + quad * 8];
    qf[h][1] = *(const bf16x8*)&Q[(size_t)(q0 + h * 16 + l16) * HDIM + 32 + quad * 8];
  }

  floatx4 o[2][4] = {};
  float lr[2] = {0.f, 0.f};

  for (int t = 0; t < 8; ++t) {
    const int tile = wave * 8 + t;
    const unsigned short* kb = Kf + (size_t)tile * 4096;
    const unsigned short* vb = Vf + (size_t)tile * 4096;
    bf16x8 kf[2][4], vf[2][4];
#pragma unroll
    for (int step = 0; step < 2; ++step)
#pragma unroll
      for (int g = 0; g < 4; ++g) {
        kf[step][g] = *(const bf16x8*)&kb[(step * 4 + g) * 512 + lane * 8];
        vf[step][g] = *(const bf16x8*)&vb[(step * 4 + g) * 512 + lane * 8];
      }

    // S^T = K Q^T, both q-halves share each K fragment
    floatx4 s[2][4] = {};
#pragma unroll
    for (int step = 0; step < 2; ++step)
#pragma unroll
      for (int mt = 0; mt < 4; ++mt) {
        s[0][mt] = __builtin_amdgcn_mfma_f32_16x16x32_bf16(kf[step][mt], qf[0][step], s[0][mt], 0, 0, 0);
        s[1][mt] = __builtin_amdgcn_mfma_f32_16x16x32_bf16(kf[step][mt], qf[1][step], s[1][mt], 0, 0, 0);
      }

    // max-free softmax: p = exp2(s'), accumulate l per-lane, pack P -> LDS
#pragma unroll
    for (int h = 0; h < 2; ++h) {
#pragma unroll
      for (int mt = 0; mt < 4; ++mt) {
        float p0 = __builtin_amdgcn_exp2f(s[h][mt][0]);
        float p1 = __builtin_amdgcn_exp2f(s[h][mt][1]);
        float p2 = __builtin_amdgcn_exp2f(s[h][mt][2]);
        float p3 = __builtin_amdgcn_exp2f(s[h][mt][3]);
        lr[h] += (p0 + p1) + (p2 + p3);
        uint2 pv;
        pv.x = pk2bf(p0, p1);
        pv.y = pk2bf(p2, p3);
        *(uint2*)&Pl[wave][(h * 16 + l16) * 72 + mt * 16 + quad * 4] = pv;
      }
    }
    // per-wave LDS RAW: drain ds queue; clobber stops compiler reordering
    __asm__ __volatile__("s_waitcnt lgkmcnt(0)" ::: "memory");

    // O += P V, both halves share each V fragment
#pragma unroll
    for (int step = 0; step < 2; ++step) {
      const int kk = step * 32 + quad * 8;
      bf16x8 pf0 = *(const bf16x8*)&Pl[wave][(l16) * 72 + kk];
      bf16x8 pf1 = *(const bf16x8*)&Pl[wave][(16 + l16) * 72 + kk];
#pragma unroll
      for (int j = 0; j < 4; ++j) {
        o[0][j] = __builtin_amdgcn_mfma_f32_16x16x32_bf16(pf0, vf[step][j], o[0][j], 0, 0, 0);
        o[1][j] = __builtin_amdgcn_mfma_f32_16x16x32_bf16(pf1, vf[step][j], o[1][j], 0, 0, 0);
      }
    }
  }

  // reduce l across the 4 quads holding each q-row
#pragma unroll
  for (int h = 0; h < 2; ++h) {
    lr[h] += __shfl_xor(lr[h], 16, 64);
    lr[h] += __shfl_xor(lr[h], 32, 64);
  }

  // waves 1..3: dump partials into own Pl slot (dead after the loop)
  if (wave != 0) {
#pragma unroll
    for (int h = 0; h < 2; ++h) {
      if (quad == 0)
        *(float*)&Pl[wave][2048 + 2 * (h * 16 + l16)] = lr[h];
#pragma unroll
      for (int j = 0; j < 4; ++j)
#pragma unroll
        for (int r = 0; r < 4; ++r)
          Pl[wave][(h * 16 + quad * 4 + r) * 64 + j * 16 + l16] =
              f2bf(o[h][j][r]);
    }
  }
  __syncthreads();

  if (wave == 0) {
    unsigned short* cp = ctx + slab;
#pragma unroll
    for (int h = 0; h < 2; ++h) {
      float lt = lr[h];
#pragma unroll
      for (int p = 1; p < 4; ++p)
        lt += *(const float*)&Pl[p][2048 + 2 * (h * 16 + l16)];
      float lb[4];
#pragma unroll
      for (int r = 0; r < 4; ++r)
        lb[r] = 1.0f / __shfl(lt, quad * 4 + r, 64);
#pragma unroll
      for (int j = 0; j < 4; ++j)
#pragma unroll
        for (int r = 0; r < 4; ++r) {
          const int row = h * 16 + quad * 4 + r;
          float v = o[h][j][r];
#pragma unroll
          for (int p = 1; p < 4; ++p)
            v += __uint_as_float(
                (unsigned int)Pl[p][row * 64 + j * 16 + l16] << 16);
          cp[(size_t)(q0 + row) * HDIM + j * 16 + l16] = f2bf(v * lb[r]);
        }
    }
  }
}

// ---- residual + LayerNorm + exact GELU (erf), one block per row, float4 ----
__global__ __launch_bounds__(256) void ln_gelu(
    const float* __restrict__ x, const float* __restrict__ y,
    const float* __restrict__ gamma, const float* __restrict__ beta,
    float* __restrict__ out) {
  const int row = blockIdx.x;
  const int tid = threadIdx.x;
  const float4 xv = ((const float4*)(x + (size_t)row * DIM))[tid];
  const float4 yv = ((const float4*)(y + (size_t)row * DIM))[tid];
  float4 s;
  s.x = xv.x + yv.x; s.y = xv.y + yv.y; s.z = xv.z + yv.z; s.w = xv.w + yv.w;
  float sum = (s.x + s.y) + (s.z + s.w);
  float sq  = (s.x * s.x + s.y * s.y) + (s.z * s.z + s.w * s.w);
#pragma unroll
  for (int off = 1; off < 64; off <<= 1) {
    sum += __shfl_xor(sum, off, 64);
    sq  += __shfl_xor(sq, off, 64);
  }
  __shared__ float red[8];
  const int wave = tid >> 6, lane = tid & 63;
  if (lane == 0) { red[wave] = sum; red[wave + 4] = sq; }
  __syncthreads();
  sum = red[0] + red[1] + red[2] + red[3];
  sq  = red[4] + red[5] + red[6] + red[7];
  const float mu   = sum * (1.0f / DIM);
  const float var  = sq * (1.0f / DIM) - mu * mu;
  const float rstd = rsqrtf(var + 1e-5f);
  const float4 gv = ((const float4*)gamma)[tid];
  const float4 bv = ((const float4*)beta)[tid];
  float4 ov;
  {
    const float v = (s.x - mu) * rstd * gv.x + bv.x;
    ov.x = 0.5f * v * (1.0f + erff(v * 0.70710678118654752f));
  }
  {
    const float v = (s.y - mu) * rstd * gv.y + bv.y;
    ov.y = 0.5f * v * (1.0f + erff(v * 0.70710678118654752f));
  }
  {
    const float v = (s.z - mu) * rstd * gv.z + bv.z;
    ov.z = 0.5f * v * (1.0f + erff(v * 0.70710678118654752f));
  }
  {
    const float v = (s.w - mu) * rstd * gv.w + bv.w;
    ov.w = 0.5f * v * (1.0f + erff(v * 0.70710678118654752f));
  }
  ((float4*)(out + (size_t)row * DIM))[tid] = ov;
}

// ---------------------------------------------------------------------------
extern "C" void kernel_launch(void* const* d_in, const int* in_sizes, int n_in,
                              void* d_out, int out_size, void* d_ws, size_t ws_size,
                              hipStream_t stream) {
  (void)in_sizes; (void)n_in; (void)out_size; (void)ws_size;
  const float* x     = (const float*)d_in[0];
  const float* Wq    = (const float*)d_in[1];
  const float* bq    = (const float*)d_in[2];
  const float* Wk    = (const float*)d_in[3];
  const float* bk    = (const float*)d_in[4];
  const float* Wv    = (const float*)d_in[5];
  const float* bv    = (const float*)d_in[6];
  const float* Wo    = (const float*)d_in[7];
  const float* bo    = (const float*)d_in[8];
  const float* gamma = (const float*)d_in[9];
  const float* beta  = (const float*)d_in[10];
  float* out = (float*)d_out;

  // Workspace (64 MB), lifetime-aliased:
  //  0- 8: xb            | 8-14: Wqkvt | 14-16: Wot
  // 16-24: Qb            | 24-32: Kb -> Ks (in-place swizzle)
  // 32-40: Vs            | 40-48: Vb (dead after swizzle) / Cx
  // 48-64: Y
  char* ws = (char*)d_ws;
  const size_t MB = 1u << 20;
  unsigned short* xb    = (unsigned short*)(ws);
  unsigned short* Wqkvt = (unsigned short*)(ws + 8 * MB);
  unsigned short* Wot   = (unsigned short*)(ws + 14 * MB);
  unsigned short* Qb    = (unsigned short*)(ws + 16 * MB);
  unsigned short* Kb    = (unsigned short*)(ws + 24 * MB);
  unsigned short* Vs    = (unsigned short*)(ws + 32 * MB);
  unsigned short* Vb    = (unsigned short*)(ws + 40 * MB);
  unsigned short* Cx    = (unsigned short*)(ws + 40 * MB);
  float*          Y     = (float*)(ws + 48 * MB);

  prep_all<<<dim3(32, 32, 5), dim3(32, 8), 0, stream>>>(x, Wq, Wk, Wv, Wo,
                                                        xb, Wqkvt, Wot);
  gemm_qkv<<<dim3(24, 32), 256, 0, stream>>>(xb, Wqkvt, bq, bk, bv, Qb, Kb, Vb);
  swizzle_kv<<<dim3(SEQ / 64, 32, 2), 256, 0, stream>>>(Kb, Vb, Vs);
  attn_fwd<<<2048, 256, 0, stream>>>(Qb, Kb, Vs, Cx);
  gemm_o<<<dim3(16, 32), 256, 0, stream>>>(Cx, Wot, bo, Y);
  ln_gelu<<<ROWS, 256, 0, stream>>>(x, Y, gamma, beta, out);
}

// Round 14
// 214.339 us; speedup vs baseline: 1.3872x; 1.0199x over previous
//
#include <hip/hip_runtime.h>
#include <hip/hip_bf16.h>
#include <cstdint>
#include <cstddef>

// ---------------------------------------------------------------------------
// MultiheadSelfAttention fused pipeline for MI355X (gfx950)
// Head bh = contiguous slab of the FLAT projection output (torch-faithful
// reshape without transpose): slab = (2048,64) row-major at bh*131072.
// Q pre-scaled by 0.125*log2(e) in gemm_qkv; MAX-FREE exp2 softmax.
// Round 14: in-block SPLIT-K x2 attention — 4 waves = (2 q-groups of 32
// rows) x (2 key-halves). Per-wave loop is 16 tiles (R12's proven
// amortization; R13's 8-tile loops regressed 54->61 us), merge is in-LDS
// and PARALLELIZED across all 256 threads (R13's wave-0-serial merge was a
// stall). No merge kernel, no global partials. XCD decode keeps 4 heads
// per XCD (FETCH 86->12 MB, R12-measured).
// ---------------------------------------------------------------------------

#define SEQ   2048
#define DIM   1024
#define NHEAD 16
#define HDIM  64
#define ROWS  4096   // B*S

#define QSCALE 0.1803368801111204f   // 0.125 * log2(e)

typedef __attribute__((ext_vector_type(8))) __bf16 bf16x8;
typedef __attribute__((ext_vector_type(4))) float floatx4;
typedef __attribute__((ext_vector_type(8))) unsigned short ushortx8;

__device__ __forceinline__ unsigned short f2bf(float f) {
  unsigned int u = __float_as_uint(f);
  u += 0x7FFFu + ((u >> 16) & 1u);   // round-to-nearest-even
  return (unsigned short)(u >> 16);
}

__device__ __forceinline__ unsigned int pk2bf(float a, float b) {
  float2 f; f.x = a; f.y = b;                       // x -> low 16
  __hip_bfloat162 h = __float22bfloat162_rn(f);
  return *(unsigned int*)&h;
}

// async global->LDS, 16B/lane; LDS dest = wave-uniform base + lane*16 (m104)
__device__ __forceinline__ void glds16(const unsigned short* g,
                                       unsigned short* l) {
  __builtin_amdgcn_global_load_lds(
      (const __attribute__((address_space(1))) void*)g,
      (__attribute__((address_space(3))) void*)l, 16, 0, 0);
}

// ---- prep: z=0..3 -> 1024x1024 fp32 W -> transposed bf16; z=4 -> cvt x -----
__global__ __launch_bounds__(256) void prep_all(
    const float* __restrict__ x,
    const float* __restrict__ Wq, const float* __restrict__ Wk,
    const float* __restrict__ Wv, const float* __restrict__ Wo,
    unsigned short* __restrict__ xb,
    unsigned short* __restrict__ Wqkvt, unsigned short* __restrict__ Wot) {
  __shared__ float t[32][33];
  const int z = blockIdx.z;
  const int tx = threadIdx.x, ty = threadIdx.y;
  if (z == 4) {   // x fp32 -> bf16, 1024 blocks x 1024 float4-chunks
    const int bid = blockIdx.y * 32 + blockIdx.x;
    const int tid = ty * 32 + tx;
#pragma unroll
    for (int p = 0; p < 4; ++p) {
      const int i = bid * 1024 + p * 256 + tid;
      float4 v = ((const float4*)x)[i];
      ushort4 o;
      o.x = f2bf(v.x); o.y = f2bf(v.y); o.z = f2bf(v.z); o.w = f2bf(v.w);
      ((ushort4*)xb)[i] = o;
    }
    return;
  }
  const float* in = (z == 0) ? Wq : (z == 1) ? Wk : (z == 2) ? Wv : Wo;
  unsigned short* out = (z < 3) ? Wqkvt + (size_t)z * DIM * DIM : Wot;
  const int bx = blockIdx.x * 32, by = blockIdx.y * 32;
#pragma unroll
  for (int i = ty; i < 32; i += 8)
    t[i][tx] = in[(size_t)(by + i) * DIM + bx + tx];
  __syncthreads();
#pragma unroll
  for (int i = ty; i < 32; i += 8)
    out[(size_t)(bx + i) * DIM + by + tx] = f2bf(t[tx][i]);
}

// ---- swizzle K (in-place) and V (from projection layout) to frag-major -----
// Tile (64 keys x 64 ch) of BOTH K and V is the contiguous 8KB block at
// slab + tile*4096 (slab view). Frag f=step*4+g is 64 lanes x 16B contiguous:
//   K: frag[lane] = K[key = g*16+l16][step*32+quad*8 ..+7]     (row copy)
//   V: frag[lane] = V[key = step*32+quad*8+e][d = g*16+l16]    (transpose)
__global__ __launch_bounds__(256) void swizzle_kv(
    unsigned short* __restrict__ Kb,         // in/out (in-place)
    const unsigned short* __restrict__ Vb,   // in (projection layout)
    unsigned short* __restrict__ Vs) {       // out fragment-major
  __shared__ unsigned short t[64 * 72];
  const int tile = blockIdx.x;               // 0..31 (key tile)
  const int bh   = blockIdx.y;               // 0..31
  const int isV  = blockIdx.z;
  const int tid  = threadIdx.x;
  const size_t base = (size_t)bh * (SEQ * HDIM) + (size_t)tile * 4096;
  const unsigned short* src = (isV ? Vb : Kb) + base;
#pragma unroll
  for (int p = 0; p < 2; ++p) {
    const int c = p * 256 + tid;
    *(ushortx8*)&t[(c >> 3) * 72 + (c & 7) * 8] = *(const ushortx8*)&src[c * 8];
  }
  __syncthreads();
  unsigned short* dst = (isV ? Vs : Kb) + base;
  const int lane = tid & 63, wave = tid >> 6;
  const int l16 = lane & 15, quad = lane >> 4;
  if (!isV) {
#pragma unroll
    for (int p = 0; p < 2; ++p) {
      const int f = wave * 2 + p;
      const int step = f >> 2, g = f & 3;
      *(ushortx8*)&dst[f * 512 + lane * 8] =
          *(const ushortx8*)&t[(g * 16 + l16) * 72 + step * 32 + quad * 8];
    }
  } else {
#pragma unroll
    for (int p = 0; p < 2; ++p) {
      const int f = wave * 2 + p;
      const int step = f >> 2, g = f & 3;
      ushortx8 v;
#pragma unroll
      for (int e = 0; e < 8; ++e)
        v[e] = t[(step * 32 + quad * 8 + e) * 72 + g * 16 + l16];
      *(ushortx8*)&dst[f * 512 + lane * 8] = v;
    }
  }
}

// ---------------------------------------------------------------------------
// Fused QKV GEMM, global_load_lds staging (m97 pattern). Unpadded LDS tiles.
// Q written PRE-SCALED by QSCALE (max-free exp2 softmax).
// ---------------------------------------------------------------------------
__global__ __launch_bounds__(256, 3) void gemm_qkv(
    const unsigned short* __restrict__ A,    // 4096 x 1024 bf16
    const unsigned short* __restrict__ Wt,   // 3072 x 1024 bf16
    const float* __restrict__ bq, const float* __restrict__ bk,
    const float* __restrict__ bv,
    unsigned short* __restrict__ Qb, unsigned short* __restrict__ Kb,
    unsigned short* __restrict__ Vb) {
  constexpr int K = DIM;
  __shared__ unsigned short As[128 * 64];    // unpadded (glds layout)
  __shared__ unsigned short Bs[128 * 64];
  const int tid  = threadIdx.x;
  const int lane = tid & 63, wave = tid >> 6;
  const int l16  = lane & 15, quad = lane >> 4;
  const int wm   = (wave & 1) * 64, wn = (wave >> 1) * 64;
  const int tm   = blockIdx.y * 128, tn = blockIdx.x * 128;
  const int grow = lane >> 3, gcol = (lane & 7) * 8;   // lane's 16B chunk

  floatx4 acc[4][4] = {};

  for (int k0 = 0; k0 < K; k0 += 64) {
    __syncthreads();
#pragma unroll
    for (int p = 0; p < 4; ++p) {
      const int q = wave * 4 + p;            // inst 0..15, rows 8q..8q+7
      const int row = q * 8 + grow;
      glds16(&A [(size_t)(tm + row) * K + k0 + gcol], &As[q * 512]);
      glds16(&Wt[(size_t)(tn + row) * K + k0 + gcol], &Bs[q * 512]);
    }
    __syncthreads();
#pragma unroll
    for (int step = 0; step < 2; ++step) {
      const int kk = step * 32 + quad * 8;
      bf16x8 af[4], bfr[4];
#pragma unroll
      for (int i = 0; i < 4; ++i)
        af[i] = *(const bf16x8*)&As[(wm + i * 16 + l16) * 64 + kk];
#pragma unroll
      for (int j = 0; j < 4; ++j)
        bfr[j] = *(const bf16x8*)&Bs[(wn + j * 16 + l16) * 64 + kk];
#pragma unroll
      for (int i = 0; i < 4; ++i)
#pragma unroll
        for (int j = 0; j < 4; ++j)
          acc[i][j] = __builtin_amdgcn_mfma_f32_16x16x32_bf16(af[i], bfr[j],
                                                              acc[i][j], 0, 0, 0);
    }
  }

#pragma unroll
  for (int j = 0; j < 4; ++j) {
    const int ng  = tn + wn + j * 16 + l16;   // output channel 0..3071
    const int seg = ng >> 10;                 // 0=Q 1=K 2=V
    const int col = ng & 1023;
    const float* bp    = (seg == 0) ? bq : (seg == 1) ? bk : bv;
    unsigned short* op = (seg == 0) ? Qb : (seg == 1) ? Kb : Vb;
    const float bias = bp[col];
    const float scl  = (seg == 0) ? QSCALE : 1.0f;
#pragma unroll
    for (int i = 0; i < 4; ++i) {
      const int m0 = tm + wm + i * 16 + quad * 4;
#pragma unroll
      for (int r = 0; r < 4; ++r)
        op[(size_t)(m0 + r) * DIM + col] = f2bf((acc[i][j][r] + bias) * scl);
    }
  }
}

// ---- Output projection GEMM: Y = ctx @ Wo + bo. 128x64 tiles (512 blocks),
// global_load_lds staging. ----------------------------------------------------
__global__ __launch_bounds__(256) void gemm_o(
    const unsigned short* __restrict__ A,    // 4096 x 1024 bf16 (ctx)
    const unsigned short* __restrict__ Wt,   // 1024 x 1024 bf16 (Wo^T)
    const float* __restrict__ bo,
    float* __restrict__ Y) {
  constexpr int K = DIM;
  __shared__ unsigned short As[128 * 64];    // unpadded (glds layout)
  __shared__ unsigned short Bs[64 * 64];
  const int tid  = threadIdx.x;
  const int lane = tid & 63, wave = tid >> 6;
  const int l16  = lane & 15, quad = lane >> 4;
  const int wm   = wave * 32;                 // wave owns 32 rows, all 64 cols
  const int tm   = blockIdx.y * 128, tn = blockIdx.x * 64;
  const int grow = lane >> 3, gcol = (lane & 7) * 8;

  floatx4 acc[2][4] = {};

  for (int k0 = 0; k0 < K; k0 += 64) {
    __syncthreads();
#pragma unroll
    for (int p = 0; p < 4; ++p) {
      const int q = wave * 4 + p;            // 0..15
      const int row = q * 8 + grow;
      glds16(&A[(size_t)(tm + row) * K + k0 + gcol], &As[q * 512]);
    }
#pragma unroll
    for (int p = 0; p < 2; ++p) {
      const int q = wave * 2 + p;            // 0..7
      const int row = q * 8 + grow;
      glds16(&Wt[(size_t)(tn + row) * K + k0 + gcol], &Bs[q * 512]);
    }
    __syncthreads();
#pragma unroll
    for (int step = 0; step < 2; ++step) {
      const int kk = step * 32 + quad * 8;
      bf16x8 af[2], bfr[4];
#pragma unroll
      for (int i = 0; i < 2; ++i)
        af[i] = *(const bf16x8*)&As[(wm + i * 16 + l16) * 64 + kk];
#pragma unroll
      for (int j = 0; j < 4; ++j)
        bfr[j] = *(const bf16x8*)&Bs[(j * 16 + l16) * 64 + kk];
#pragma unroll
      for (int i = 0; i < 2; ++i)
#pragma unroll
        for (int j = 0; j < 4; ++j)
          acc[i][j] = __builtin_amdgcn_mfma_f32_16x16x32_bf16(af[i], bfr[j],
                                                              acc[i][j], 0, 0, 0);
    }
  }

#pragma unroll
  for (int j = 0; j < 4; ++j) {
    const int n = tn + j * 16 + l16;
    const float bias = bo[n];
#pragma unroll
    for (int i = 0; i < 2; ++i) {
      const int m0 = tm + wm + i * 16 + quad * 4;
#pragma unroll
      for (int r = 0; r < 4; ++r)
        Y[(size_t)(m0 + r) * DIM + n] = acc[i][j][r] + bias;
    }
  }
}

// ---------------------------------------------------------------------------
// Flash attention, in-block SPLIT-K x2, barrier-free main loop. 1024 blocks
// x 256 thr = 16 waves/CU. Waves = (wq = wave>>1: q-group of 32 rows) x
// (wk = wave&1: key-half of 16 tiles). Max-free softmax => partials merge
// by addition: ALL waves dump bf16 O + fp32 l into their Pl slot, one
// barrier, then all 256 threads merge (16 elements each) and write ctx.
// Decode (XCD-aware, xcd=id&7): head=(id&7)*4+(w&3), qpair=w>>2, w=id>>3.
// ---------------------------------------------------------------------------
__global__ __launch_bounds__(256) void attn_fwd(
    const unsigned short* __restrict__ Qb,
    const unsigned short* __restrict__ Ks,   // fragment-major K
    const unsigned short* __restrict__ Vs,   // fragment-major V^T
    unsigned short* __restrict__ ctx) {
  // per-wave slot: P staging (32x72 shorts) during loop; afterwards partial
  // O bf16 [q*64+d] (4096B) + l fp32 at short-offset 2048 (128B).
  __shared__ unsigned short Pl[4][32 * 72];

  const int tid  = threadIdx.x;               // 0..255
  const int lane = tid & 63, wave = tid >> 6;
  const int l16  = lane & 15, quad = lane >> 4;
  const int wq   = wave >> 1, wk = wave & 1;  // q-group / key-half
  const int id   = blockIdx.x;
  const int w    = id >> 3;                   // 0..127
  const int head = (id & 7) * 4 + (w & 3);    // 4 heads per XCD
  const int qp   = w >> 2;                    // 0..31
  const size_t slab = (size_t)head * SEQ * HDIM;
  const unsigned short* Q  = Qb + slab;
  const unsigned short* Kf = Ks + slab;
  const unsigned short* Vf = Vs + slab;
  const int q0 = qp * 64 + wq * 32;

  // Q fragments (pre-scaled by QSCALE): B-operand, halves h=0,1
  bf16x8 qf[2][2];
#pragma unroll
  for (int h = 0; h < 2; ++h) {
    qf[h][0] = *(const bf16x8*)&Q[(size_t)(q0 + h * 16 + l16) * HDIM + quad * 8];
    qf[h][1] = *(const bf16x8*)&Q[(size_t)(q0 + h * 16 + l16) * HDIM + 32 + quad * 8];
  }

  floatx4 o[2][4] = {};
  float lr[2] = {0.f, 0.f};

  for (int t = 0; t < 16; ++t) {
    const int tile = wk * 16 + t;
    const unsigned short* kb = Kf + (size_t)tile * 4096;
    const unsigned short* vb = Vf + (size_t)tile * 4096;
    bf16x8 kf[2][4], vf[2][4];
#pragma unroll
    for (int step = 0; step < 2; ++step)
#pragma unroll
      for (int g = 0; g < 4; ++g) {
        kf[step][g] = *(const bf16x8*)&kb[(step * 4 + g) * 512 + lane * 8];
        vf[step][g] = *(const bf16x8*)&vb[(step * 4 + g) * 512 + lane * 8];
      }

    // S^T = K Q^T, both q-halves share each K fragment
    floatx4 s[2][4] = {};
#pragma unroll
    for (int step = 0; step < 2; ++step)
#pragma unroll
      for (int mt = 0; mt < 4; ++mt) {
        s[0][mt] = __builtin_amdgcn_mfma_f32_16x16x32_bf16(kf[step][mt], qf[0][step], s[0][mt], 0, 0, 0);
        s[1][mt] = __builtin_amdgcn_mfma_f32_16x16x32_bf16(kf[step][mt], qf[1][step], s[1][mt], 0, 0, 0);
      }

    // max-free softmax: p = exp2(s'), accumulate l per-lane, pack P -> LDS
#pragma unroll
    for (int h = 0; h < 2; ++h) {
#pragma unroll
      for (int mt = 0; mt < 4; ++mt) {
        float p0 = __builtin_amdgcn_exp2f(s[h][mt][0]);
        float p1 = __builtin_amdgcn_exp2f(s[h][mt][1]);
        float p2 = __builtin_amdgcn_exp2f(s[h][mt][2]);
        float p3 = __builtin_amdgcn_exp2f(s[h][mt][3]);
        lr[h] += (p0 + p1) + (p2 + p3);
        uint2 pv;
        pv.x = pk2bf(p0, p1);
        pv.y = pk2bf(p2, p3);
        *(uint2*)&Pl[wave][(h * 16 + l16) * 72 + mt * 16 + quad * 4] = pv;
      }
    }
    // per-wave LDS RAW: drain ds queue; clobber stops compiler reordering
    __asm__ __volatile__("s_waitcnt lgkmcnt(0)" ::: "memory");

    // O += P V, both halves share each V fragment
#pragma unroll
    for (int step = 0; step < 2; ++step) {
      const int kk = step * 32 + quad * 8;
      bf16x8 pf0 = *(const bf16x8*)&Pl[wave][(l16) * 72 + kk];
      bf16x8 pf1 = *(const bf16x8*)&Pl[wave][(16 + l16) * 72 + kk];
#pragma unroll
      for (int j = 0; j < 4; ++j) {
        o[0][j] = __builtin_amdgcn_mfma_f32_16x16x32_bf16(pf0, vf[step][j], o[0][j], 0, 0, 0);
        o[1][j] = __builtin_amdgcn_mfma_f32_16x16x32_bf16(pf1, vf[step][j], o[1][j], 0, 0, 0);
      }
    }
  }

  // reduce l across the 4 quads holding each q-row
#pragma unroll
  for (int h = 0; h < 2; ++h) {
    lr[h] += __shfl_xor(lr[h], 16, 64);
    lr[h] += __shfl_xor(lr[h], 32, 64);
  }

  // ALL waves dump partials into own Pl slot (dead after the loop):
  // O bf16 row-major [q*64+d], l fp32 at short-offset 2048+2q.
#pragma unroll
  for (int h = 0; h < 2; ++h) {
    if (quad == 0)
      *(float*)&Pl[wave][2048 + 2 * (h * 16 + l16)] = lr[h];
#pragma unroll
    for (int j = 0; j < 4; ++j)
#pragma unroll
      for (int r = 0; r < 4; ++r)
        Pl[wave][(h * 16 + quad * 4 + r) * 64 + j * 16 + l16] =
            f2bf(o[h][j][r]);
  }
  __syncthreads();

  // parallel merge: thread t -> q-group g=t>>7, q=(t&127)>>2, d0=(t&3)*16.
  // slots 2g (wk=0) and 2g+1 (wk=1). ctx write is lane-contiguous (u*32B).
  {
    const int g = tid >> 7, u = tid & 127;
    const int q = u >> 2, d0 = (u & 3) * 16;
    const int sa = g * 2, sb = g * 2 + 1;
    const float lt = *(const float*)&Pl[sa][2048 + 2 * q] +
                     *(const float*)&Pl[sb][2048 + 2 * q];
    const float inv = 1.0f / lt;
    unsigned short* cp = ctx + slab + (size_t)(qp * 64 + g * 32 + q) * HDIM;
#pragma unroll
    for (int c = 0; c < 2; ++c) {
      ushortx8 a = *(const ushortx8*)&Pl[sa][q * 64 + d0 + c * 8];
      ushortx8 b = *(const ushortx8*)&Pl[sb][q * 64 + d0 + c * 8];
      ushortx8 ov;
#pragma unroll
      for (int e = 0; e < 8; ++e) {
        const float fa = __uint_as_float((unsigned int)a[e] << 16);
        const float fb = __uint_as_float((unsigned int)b[e] << 16);
        ov[e] = f2bf((fa + fb) * inv);
      }
      *(ushortx8*)&cp[d0 + c * 8] = ov;
    }
  }
}

// ---- residual + LayerNorm + exact GELU (erf), one block per row, float4 ----
__global__ __launch_bounds__(256) void ln_gelu(
    const float* __restrict__ x, const float* __restrict__ y,
    const float* __restrict__ gamma, const float* __restrict__ beta,
    float* __restrict__ out) {
  const int row = blockIdx.x;
  const int tid = threadIdx.x;
  const float4 xv = ((const float4*)(x + (size_t)row * DIM))[tid];
  const float4 yv = ((const float4*)(y + (size_t)row * DIM))[tid];
  float4 s;
  s.x = xv.x + yv.x; s.y = xv.y + yv.y; s.z = xv.z + yv.z; s.w = xv.w + yv.w;
  float sum = (s.x + s.y) + (s.z + s.w);
  float sq  = (s.x * s.x + s.y * s.y) + (s.z * s.z + s.w * s.w);
#pragma unroll
  for (int off = 1; off < 64; off <<= 1) {
    sum += __shfl_xor(sum, off, 64);
    sq  += __shfl_xor(sq, off, 64);
  }
  __shared__ float red[8];
  const int wave = tid >> 6, lane = tid & 63;
  if (lane == 0) { red[wave] = sum; red[wave + 4] = sq; }
  __syncthreads();
  sum = red[0] + red[1] + red[2] + red[3];
  sq  = red[4] + red[5] + red[6] + red[7];
  const float mu   = sum * (1.0f / DIM);
  const float var  = sq * (1.0f / DIM) - mu * mu;
  const float rstd = rsqrtf(var + 1e-5f);
  const float4 gv = ((const float4*)gamma)[tid];
  const float4 bv = ((const float4*)beta)[tid];
  float4 ov;
  {
    const float v = (s.x - mu) * rstd * gv.x + bv.x;
    ov.x = 0.5f * v * (1.0f + erff(v * 0.70710678118654752f));
  }
  {
    const float v = (s.y - mu) * rstd * gv.y + bv.y;
    ov.y = 0.5f * v * (1.0f + erff(v * 0.70710678118654752f));
  }
  {
    const float v = (s.z - mu) * rstd * gv.z + bv.z;
    ov.z = 0.5f * v * (1.0f + erff(v * 0.70710678118654752f));
  }
  {
    const float v = (s.w - mu) * rstd * gv.w + bv.w;
    ov.w = 0.5f * v * (1.0f + erff(v * 0.70710678118654752f));
  }
  ((float4*)(out + (size_t)row * DIM))[tid] = ov;
}

// ---------------------------------------------------------------------------
extern "C" void kernel_launch(void* const* d_in, const int* in_sizes, int n_in,
                              void* d_out, int out_size, void* d_ws, size_t ws_size,
                              hipStream_t stream) {
  (void)in_sizes; (void)n_in; (void)out_size; (void)ws_size;
  const float* x     = (const float*)d_in[0];
  const float* Wq    = (const float*)d_in[1];
  const float* bq    = (const float*)d_in[2];
  const float* Wk    = (const float*)d_in[3];
  const float* bk    = (const float*)d_in[4];
  const float* Wv    = (const float*)d_in[5];
  const float* bv    = (const float*)d_in[6];
  const float* Wo    = (const float*)d_in[7];
  const float* bo    = (const float*)d_in[8];
  const float* gamma = (const float*)d_in[9];
  const float* beta  = (const float*)d_in[10];
  float* out = (float*)d_out;

  // Workspace (64 MB), lifetime-aliased:
  //  0- 8: xb            | 8-14: Wqkvt | 14-16: Wot
  // 16-24: Qb            | 24-32: Kb -> Ks (in-place swizzle)
  // 32-40: Vs            | 40-48: Vb (dead after swizzle) / Cx
  // 48-64: Y
  char* ws = (char*)d_ws;
  const size_t MB = 1u << 20;
  unsigned short* xb    = (unsigned short*)(ws);
  unsigned short* Wqkvt = (unsigned short*)(ws + 8 * MB);
  unsigned short* Wot   = (unsigned short*)(ws + 14 * MB);
  unsigned short* Qb    = (unsigned short*)(ws + 16 * MB);
  unsigned short* Kb    = (unsigned short*)(ws + 24 * MB);
  unsigned short* Vs    = (unsigned short*)(ws + 32 * MB);
  unsigned short* Vb    = (unsigned short*)(ws + 40 * MB);
  unsigned short* Cx    = (unsigned short*)(ws + 40 * MB);
  float*          Y     = (float*)(ws + 48 * MB);

  prep_all<<<dim3(32, 32, 5), dim3(32, 8), 0, stream>>>(x, Wq, Wk, Wv, Wo,
                                                        xb, Wqkvt, Wot);
  gemm_qkv<<<dim3(24, 32), 256, 0, stream>>>(xb, Wqkvt, bq, bk, bv, Qb, Kb, Vb);
  swizzle_kv<<<dim3(SEQ / 64, 32, 2), 256, 0, stream>>>(Kb, Vb, Vs);
  attn_fwd<<<1024, 256, 0, stream>>>(Qb, Kb, Vs, Cx);
  gemm_o<<<dim3(16, 32), 256, 0, stream>>>(Cx, Wot, bo, Y);
  ln_gelu<<<ROWS, 256, 0, stream>>>(x, Y, gamma, beta, out);
}